// Round 6
// baseline (461.704 us; speedup 1.0000x reference)
//
#include <hip/hip_runtime.h>

typedef _Float16 half8 __attribute__((ext_vector_type(8)));
typedef float floatx4 __attribute__((ext_vector_type(4)));

#define NB 64
#define NN 2048
#define ND 128
#define NT 1024
#define NSEG 8
#define SEGN 256        // NN / NSEG
#define NC 16           // n-rows per chunk
#define NCHUNK 16       // SEGN / NC

// exp2-domain constants: alpha^2 = 0.5*log2(e); scaling W,targets by alpha
// makes (alpha*d)^2 sums directly usable as log2 exponents.
#define ALPHA 0.84932184f
#define INV_ALPHA 1.17741002f
#define LP2_MAJOR (-1.7369655941662063f)   // log2(0.9/3)
#define LP2_MINOR (-12.321928094887362f)   // log2(0.1/512)

// bare v_exp_f32 (input already in log2 units, always <= 0 here)
__device__ __forceinline__ float fexp2(float x) {
  float r;
  asm("v_exp_f32 %0, %1" : "=v"(r) : "v"(x));
  return r;
}

// DPP row_shr add step for 16-lane inclusive scan (zero-fill at row edge)
template <int CTRL>
__device__ __forceinline__ float dppshr_add(float x) {
  int i = __builtin_bit_cast(int, x);
  int s = __builtin_amdgcn_update_dpp(0, i, CTRL, 0xF, 0xF, true);
  return x + __builtin_bit_cast(float, s);
}
// inclusive scan over l15 within each 16-lane row
__device__ __forceinline__ float scan16(float x) {
  x = dppshr_add<0x111>(x);   // row_shr:1
  x = dppshr_add<0x112>(x);   // row_shr:2
  x = dppshr_add<0x114>(x);   // row_shr:4
  x = dppshr_add<0x118>(x);   // row_shr:8
  return x;
}
// broadcast row-lane-15 value to all 16 lanes of the row
__device__ __forceinline__ float bcast15(float x) {
  int i = __builtin_bit_cast(int, x);
  i = __builtin_amdgcn_ds_swizzle(i, 0x1F0);
  return __builtin_bit_cast(float, i);
}

// ---- prep: W_all (f32, [D][T]) -> alpha-scaled t-major f16 hi/lo [t][d] ------
__global__ void k_prep(const float* __restrict__ W, const float* __restrict__ Wm,
                       _Float16* __restrict__ Wph, _Float16* __restrict__ Wpl) {
  int idx = blockIdx.x * 256 + threadIdx.x;      // 131072 = 1024*128
  int t = idx >> 7, d = idx & 127;
  float x = (t < 512) ? W[d * 512 + t] : Wm[d * 512 + (t - 512)];
  x *= ALPHA;
  _Float16 h = (_Float16)x;
  _Float16 l = (_Float16)(x - (float)h);
  Wph[idx] = h;
  Wpl[idx] = l;
}

// ---- prep: data (f32 [B][N][D]) -> fragment-packed f16 hi/lo (NT stores) -----
__global__ void k_prep_data(const float* __restrict__ data,
                            _Float16* __restrict__ Ahp, _Float16* __restrict__ Alp) {
  int idx = blockIdx.x * 256 + threadIdx.x;      // 2,097,152 threads
  int l = idx & 63, kk = (idx >> 6) & 3, ch = (idx >> 8) & 127, b = idx >> 15;
  int row = ch * 16 + (l & 15);
  int dcol = kk * 32 + (l >> 4) * 8;
  const float* src = data + ((size_t)b * NN + row) * ND + dcol;
  floatx4 a0 = *(const floatx4*)src;
  floatx4 a1 = *(const floatx4*)(src + 4);
  half8 h, lo;
#pragma unroll
  for (int j = 0; j < 4; ++j) {
    h[j] = (_Float16)a0[j];
    lo[j] = (_Float16)(a0[j] - (float)h[j]);
    h[4 + j] = (_Float16)a1[j];
    lo[4 + j] = (_Float16)(a1[j] - (float)h[4 + j]);
  }
  size_t o = (size_t)idx * 8;
  __builtin_nontemporal_store(h, (half8*)(Ahp + o));
  __builtin_nontemporal_store(lo, (half8*)(Alp + o));
}

// ---- W-fragment load (same lane pattern serves A- or B-operand role) ---------
__device__ __forceinline__ void load_wfrags(const _Float16* __restrict__ Wph,
                                            const _Float16* __restrict__ Wpl,
                                            int tbase, int l15, int lhi,
                                            half8 (&wh)[2][4], half8 (&wl)[2][4]) {
#pragma unroll
  for (int tt = 0; tt < 2; ++tt)
#pragma unroll
    for (int kk = 0; kk < 4; ++kk) {
      int t = tbase + tt * 16 + l15;
      int off = t * 128 + kk * 32 + lhi * 8;
      wh[tt][kk] = *(const half8*)(Wph + off);
      wl[tt][kk] = *(const half8*)(Wpl + off);
    }
}

// in-loop residency pin: asm nominally rewrites the frags each iteration, so
// the compiler cannot rematerialize them from memory -> true loop-carried regs
#define PIN_FRAGS(wh, wl)                                   \
  do {                                                      \
    _Pragma("unroll")                                       \
    for (int tt = 0; tt < 2; ++tt)                          \
      _Pragma("unroll")                                     \
      for (int kk = 0; kk < 4; ++kk)                        \
        asm volatile("" : "+v"(wh[tt][kk]), "+v"(wl[tt][kk])); \
  } while (0)

// ---- pass A: per (b, seg, tblock): sum of (alpha*diff)^2 over segment per t --
__global__ __launch_bounds__(256, 4)
void k_segsum(const _Float16* __restrict__ Ahp, const _Float16* __restrict__ Alp,
              const float* __restrict__ targets,
              const _Float16* __restrict__ Wph, const _Float16* __restrict__ Wpl,
              float* __restrict__ segsum) {
  int bid = blockIdx.x;
  int seg = bid & 7, tb = (bid >> 3) & 7, b = bid >> 6;   // seg -> XCD
  int tid = threadIdx.x;
  int w = tid >> 6, l = tid & 63;
  int l15 = l & 15, lhi = l >> 4;

  half8 wh[2][4], wl[2][4];
  load_wfrags(Wph, Wpl, tb * 128 + w * 32, l15, lhi, wh, wl);

  int nseg0 = seg * SEGN;
  const _Float16* ahp = Ahp + ((size_t)b * 128 + seg * 16) * 2048;
  const _Float16* alp = Alp + ((size_t)b * 128 + seg * 16) * 2048;
  const float* tgp = targets + (size_t)b * NN + nseg0 + lhi * 4;

  float accs[2] = {0.f, 0.f};
  floatx4 accf[2];
  for (int ch = 0; ch < NCHUNK; ++ch) {
    PIN_FRAGS(wh, wl);
    floatx4 z = {0.f, 0.f, 0.f, 0.f};
    accf[0] = z; accf[1] = z;
#pragma unroll
    for (int kk = 0; kk < 4; ++kk) {
      half8 ah = *(const half8*)(ahp + kk * 512 + l * 8);
      half8 al = *(const half8*)(alp + kk * 512 + l * 8);
#pragma unroll
      for (int tt = 0; tt < 2; ++tt) {
        accf[tt] = __builtin_amdgcn_mfma_f32_16x16x32_f16(ah, wh[tt][kk], accf[tt], 0, 0, 0);
        accf[tt] = __builtin_amdgcn_mfma_f32_16x16x32_f16(ah, wl[tt][kk], accf[tt], 0, 0, 0);
        accf[tt] = __builtin_amdgcn_mfma_f32_16x16x32_f16(al, wh[tt][kk], accf[tt], 0, 0, 0);
      }
    }
    floatx4 tg = *(const floatx4*)tgp * ALPHA;
#pragma unroll
    for (int tt = 0; tt < 2; ++tt) {
      float d0 = tg[0] - accf[tt][0], d1 = tg[1] - accf[tt][1];
      float d2 = tg[2] - accf[tt][2], d3 = tg[3] - accf[tt][3];
      accs[tt] += d0 * d0 + d1 * d1 + d2 * d2 + d3 * d3;
    }
    ahp += 2048; alp += 2048; tgp += NC;
  }
#pragma unroll
  for (int tt = 0; tt < 2; ++tt) {
    float tot = accs[tt];
    tot += __shfl_xor(tot, 16);
    tot += __shfl_xor(tot, 32);
    if (lhi == 0)
      segsum[((size_t)b * NT + tb * 128 + w * 32 + tt * 16 + l15) * NSEG + seg] = tot;
  }
}

// ---- tiny exclusive scan over segments per (b,t) -----------------------------
__global__ void k_scan(const float* __restrict__ segsum, float* __restrict__ carry) {
  int idx = blockIdx.x * 256 + threadIdx.x;   // 65536 = NB*NT
  const float* ss = segsum + (size_t)idx * NSEG;
  float* cr = carry + (size_t)idx * NSEG;
  float a = 0.f;
#pragma unroll
  for (int s = 0; s < NSEG; ++s) { cr[s] = a; a += ss[s]; }
}

// ---- pass C (n-in-lane): col = n = l15, row = t = lhi*4+r (+tile*16) ---------
__global__ __launch_bounds__(256, 4)
void k_main(const _Float16* __restrict__ Ahp, const _Float16* __restrict__ Alp,
            const float* __restrict__ targets,
            const _Float16* __restrict__ Wph, const _Float16* __restrict__ Wpl,
            const float* __restrict__ carry, floatx4* __restrict__ part) {
  int bid = blockIdx.x;
  int seg = bid & 7, tb = (bid >> 3) & 7, b = bid >> 6;
  int tid = threadIdx.x;
  int w = tid >> 6, l = tid & 63;
  int l15 = l & 15, lhi = l >> 4;
  int tbase = tb * 128 + w * 32;

  half8 wh[2][4], wl[2][4];
  load_wfrags(Wph, Wpl, tbase, l15, lhi, wh, wl);

  float prior2 = (tb < 4) ? LP2_MAJOR : LP2_MINOR;   // t<512 <=> tb<4

  // pcc = prior2 - carry_init (constant); run accumulates this block's chunks
  float pcc[2][4], run[2][4];
#pragma unroll
  for (int tt = 0; tt < 2; ++tt)
#pragma unroll
    for (int r = 0; r < 4; ++r) {
      int t = tbase + tt * 16 + lhi * 4 + r;
      pcc[tt][r] = prior2 - carry[((size_t)b * NT + t) * NSEG + seg];
      run[tt][r] = 0.f;
    }

  int nseg0 = seg * SEGN;
  const _Float16* ahp = Ahp + ((size_t)b * 128 + seg * 16) * 2048;
  const _Float16* alp = Alp + ((size_t)b * 128 + seg * 16) * 2048;
  const float* tgp = targets + (size_t)b * NN + nseg0 + l15;
  size_t pbase = ((size_t)b * NN + nseg0) * 8 + tb;

  __shared__ float sm[4][4][16][5];   // [wave][chunk%4][n_local][{m,s1,s2,pad,pad}]
  floatx4 acc[2];
  for (int ch = 0; ch < NCHUNK; ++ch) {
    // GEMM: acc[tile][r] = alpha*XW[n = n0+l15][t = tbase + tile*16 + lhi*4 + r]
    floatx4 z = {0.f, 0.f, 0.f, 0.f};
    acc[0] = z; acc[1] = z;
#pragma unroll
    for (int kk = 0; kk < 4; ++kk) {
      half8 ah = *(const half8*)(ahp + kk * 512 + l * 8);
      half8 al = *(const half8*)(alp + kk * 512 + l * 8);
#pragma unroll
      for (int tt = 0; tt < 2; ++tt) {
        acc[tt] = __builtin_amdgcn_mfma_f32_16x16x32_f16(wh[tt][kk], ah, acc[tt], 0, 0, 0);
        acc[tt] = __builtin_amdgcn_mfma_f32_16x16x32_f16(wh[tt][kk], al, acc[tt], 0, 0, 0);
        acc[tt] = __builtin_amdgcn_mfma_f32_16x16x32_f16(wl[tt][kk], ah, acc[tt], 0, 0, 0);
      }
    }
    float tgs = tgp[0] * ALPHA;   // this lane's n; broadcast across lhi

    float q[2][4], inc[2][4], lp[2][4];
#pragma unroll
    for (int tt = 0; tt < 2; ++tt)
#pragma unroll
      for (int r = 0; r < 4; ++r) {
        float d = tgs - acc[tt][r];
        q[tt][r] = d * d;
      }
    // inclusive scan over n (l15 within 16-lane row), per t-value
#pragma unroll
    for (int tt = 0; tt < 2; ++tt)
#pragma unroll
      for (int r = 0; r < 4; ++r)
        inc[tt][r] = scan16(q[tt][r]);
    // lp = prior2 - (carry_init + run + exclusive) ; exclusive = inc - q
#pragma unroll
    for (int tt = 0; tt < 2; ++tt)
#pragma unroll
      for (int r = 0; r < 4; ++r) {
        float t1 = pcc[tt][r] - run[tt][r];
        lp[tt][r] = t1 + (q[tt][r] - inc[tt][r]);
      }
    // carry forward: row total = inc @ lane15
#pragma unroll
    for (int tt = 0; tt < 2; ++tt)
#pragma unroll
      for (int r = 0; r < 4; ++r)
        run[tt][r] += bcast15(inc[tt][r]);

    // softmax over this wave's 32 t: in-lane 8 + cross-lane xor16/32
    float m = fmaxf(fmaxf(fmaxf(lp[0][0], lp[0][1]), fmaxf(lp[0][2], lp[0][3])),
                    fmaxf(fmaxf(lp[1][0], lp[1][1]), fmaxf(lp[1][2], lp[1][3])));
    m = fmaxf(m, __shfl_xor(m, 16));
    m = fmaxf(m, __shfl_xor(m, 32));
    float s1 = 0.f, s2 = 0.f;
#pragma unroll
    for (int tt = 0; tt < 2; ++tt)
#pragma unroll
      for (int r = 0; r < 4; ++r) {
        float e = fexp2(lp[tt][r] - m);
        s1 += e;
        s2 = fmaf(e, acc[tt][r], s2);
      }
    s1 += __shfl_xor(s1, 16);
    s1 += __shfl_xor(s1, 32);
    s2 += __shfl_xor(s2, 16);
    s2 += __shfl_xor(s2, 32);

    if (l < 16) {
      sm[w][ch & 3][l15][0] = m;
      sm[w][ch & 3][l15][1] = s1;
      sm[w][ch & 3][l15][2] = s2;
    }
    if ((ch & 3) == 3) {               // merge 4 chunks' partials across waves
      __syncthreads();
      if (tid < 64) {
        int c4 = tid >> 4, row = tid & 15;
        float m0 = sm[0][c4][row][0], m1 = sm[1][c4][row][0];
        float m2 = sm[2][c4][row][0], m3 = sm[3][c4][row][0];
        float M = fmaxf(fmaxf(m0, m1), fmaxf(m2, m3));
        float e0 = fexp2(m0 - M), e1 = fexp2(m1 - M);
        float e2 = fexp2(m2 - M), e3 = fexp2(m3 - M);
        float S1 = sm[0][c4][row][1] * e0 + sm[1][c4][row][1] * e1 +
                   sm[2][c4][row][1] * e2 + sm[3][c4][row][1] * e3;
        float S2 = sm[0][c4][row][2] * e0 + sm[1][c4][row][2] * e1 +
                   sm[2][c4][row][2] * e2 + sm[3][c4][row][2] * e3;
        floatx4 v;
        v[0] = M; v[1] = S1; v[2] = S2; v[3] = 0.f;
        part[pbase + (size_t)((ch - 3 + c4) * 16 + row) * 8] = v;
      }
      __syncthreads();
    }
    ahp += 2048; alp += 2048; tgp += NC;
  }
}

// ---- combine 8 tb-partials per (b,n) -----------------------------------------
__global__ void k_combine(const floatx4* __restrict__ part, float* __restrict__ out) {
  int idx = blockIdx.x * 256 + threadIdx.x;   // 131072 = NB*NN
  const floatx4* p = part + (size_t)idx * 8;
  floatx4 v[8];
  float M = -3.4e38f;
#pragma unroll
  for (int j = 0; j < 8; ++j) { v[j] = p[j]; M = fmaxf(M, v[j][0]); }
  float s1 = 0.f, s2 = 0.f;
#pragma unroll
  for (int j = 0; j < 8; ++j) {
    float e = fexp2(v[j][0] - M);
    s1 += v[j][1] * e;
    s2 += v[j][2] * e;
  }
  out[idx] = s2 / s1 * INV_ALPHA;   // undo alpha scale on XW values
}

extern "C" void kernel_launch(void* const* d_in, const int* in_sizes, int n_in,
                              void* d_out, int out_size, void* d_ws, size_t ws_size,
                              hipStream_t stream) {
  const float* data    = (const float*)d_in[0];
  const float* targets = (const float*)d_in[1];
  const float* W       = (const float*)d_in[2];
  const float* Wm      = (const float*)d_in[3];
  float* out = (float*)d_out;

  char* ws = (char*)d_ws;
  const size_t MB = 1u << 20;
  _Float16* Wph  = (_Float16*)ws;                          // 256 KB
  _Float16* Wpl  = (_Float16*)(ws + 256 * 1024);           // 256 KB
  _Float16* Ahp  = (_Float16*)(ws + 512 * 1024);           // 32 MB
  _Float16* Alp  = (_Float16*)(ws + 512 * 1024 + 32 * MB); // 32 MB
  float* segsum  = (float*)(ws + 512 * 1024 + 64 * MB);    // 2 MB
  float* carry   = (float*)(ws + 512 * 1024 + 66 * MB);    // 2 MB
  floatx4* part  = (floatx4*)(ws + 512 * 1024 + 68 * MB);  // 16 MB

  k_prep<<<512, 256, 0, stream>>>(W, Wm, Wph, Wpl);
  k_prep_data<<<8192, 256, 0, stream>>>(data, Ahp, Alp);
  k_segsum<<<NB * NSEG * 8, 256, 0, stream>>>(Ahp, Alp, targets, Wph, Wpl, segsum);
  k_scan<<<(NB * NT) / 256, 256, 0, stream>>>(segsum, carry);
  k_main<<<NB * NSEG * 8, 256, 0, stream>>>(Ahp, Alp, targets, Wph, Wpl, carry, part);
  k_combine<<<(NB * NN) / 256, 256, 0, stream>>>(part, out);
}

// Round 7
// 279.826 us; speedup vs baseline: 1.6500x; 1.6500x over previous
//
#include <hip/hip_runtime.h>

typedef _Float16 half8 __attribute__((ext_vector_type(8)));
typedef float floatx4 __attribute__((ext_vector_type(4)));

#define NB 64
#define NN 2048
#define ND 128
#define NT 1024
#define NSEG 8
#define SEGN 256        // NN / NSEG
#define NC 16           // n-rows per chunk
#define NCHUNK 16       // SEGN / NC

// exp2-domain constants: alpha^2 = 0.5*log2(e); scaling W,targets by alpha
// makes (alpha*d)^2 sums directly usable as log2 exponents.
#define ALPHA 0.84932184f
#define INV_ALPHA 1.17741002f
#define LP2_MAJOR (-1.7369655941662063f)   // log2(0.9/3)
#define LP2_MINOR (-12.321928094887362f)   // log2(0.1/512)

// bare v_exp_f32 (input already in log2 units, always <= 0 here)
__device__ __forceinline__ float fexp2(float x) {
  float r;
  asm("v_exp_f32 %0, %1" : "=v"(r) : "v"(x));
  return r;
}

// keep-alive pin (r4 form: once, immediately after the loads)
#define PIN8(x) asm volatile("" : "+v"(x))

// DPP row_shr add step for 16-lane inclusive scan (zero-fill at row edge)
template <int CTRL>
__device__ __forceinline__ float dppshr_add(float x) {
  int i = __builtin_bit_cast(int, x);
  int s = __builtin_amdgcn_update_dpp(0, i, CTRL, 0xF, 0xF, true);
  return x + __builtin_bit_cast(float, s);
}
// inclusive scan over l15 within each 16-lane row
__device__ __forceinline__ float scan16(float x) {
  x = dppshr_add<0x111>(x);   // row_shr:1
  x = dppshr_add<0x112>(x);   // row_shr:2
  x = dppshr_add<0x114>(x);   // row_shr:4
  x = dppshr_add<0x118>(x);   // row_shr:8
  return x;
}
// broadcast row-lane-15 value to all 16 lanes of the row
__device__ __forceinline__ float bcast15(float x) {
  int i = __builtin_bit_cast(int, x);
  i = __builtin_amdgcn_ds_swizzle(i, 0x1F0);
  return __builtin_bit_cast(float, i);
}

// ---- prep: W_all (f32, [D][T]) -> alpha-scaled t-major f16 hi/lo [t][d] ------
__global__ void k_prep(const float* __restrict__ W, const float* __restrict__ Wm,
                       _Float16* __restrict__ Wph, _Float16* __restrict__ Wpl) {
  int idx = blockIdx.x * 256 + threadIdx.x;      // 131072 = 1024*128
  int t = idx >> 7, d = idx & 127;
  float x = (t < 512) ? W[d * 512 + t] : Wm[d * 512 + (t - 512)];
  x *= ALPHA;
  _Float16 h = (_Float16)x;
  _Float16 l = (_Float16)(x - (float)h);
  Wph[idx] = h;
  Wpl[idx] = l;
}

// ---- prep: data (f32 [B][N][D]) -> fragment-packed f16 hi/lo -----------------
__global__ void k_prep_data(const float* __restrict__ data,
                            _Float16* __restrict__ Ahp, _Float16* __restrict__ Alp) {
  int idx = blockIdx.x * 256 + threadIdx.x;      // 2,097,152 threads
  int l = idx & 63, kk = (idx >> 6) & 3, ch = (idx >> 8) & 127, b = idx >> 15;
  int row = ch * 16 + (l & 15);
  int dcol = kk * 32 + (l >> 4) * 8;
  const float* src = data + ((size_t)b * NN + row) * ND + dcol;
  floatx4 a0 = *(const floatx4*)src;
  floatx4 a1 = *(const floatx4*)(src + 4);
  half8 h, lo;
#pragma unroll
  for (int j = 0; j < 4; ++j) {
    h[j] = (_Float16)a0[j];
    lo[j] = (_Float16)(a0[j] - (float)h[j]);
    h[4 + j] = (_Float16)a1[j];
    lo[4 + j] = (_Float16)(a1[j] - (float)h[4 + j]);
  }
  size_t o = (size_t)idx * 8;
  *(half8*)(Ahp + o) = h;
  *(half8*)(Alp + o) = lo;
}

// ---- B-fragment load, r4 form: loads then PIN8 keep-alives -------------------
__device__ __forceinline__ void load_bfrags(const _Float16* __restrict__ Wph,
                                            const _Float16* __restrict__ Wpl,
                                            int tbase, int l15, int lhi,
                                            half8 (&bh)[2][4], half8 (&bl)[2][4]) {
#pragma unroll
  for (int tt = 0; tt < 2; ++tt)
#pragma unroll
    for (int kk = 0; kk < 4; ++kk) {
      int t = tbase + tt * 16 + l15;
      int off = t * 128 + kk * 32 + lhi * 8;
      bh[tt][kk] = *(const half8*)(Wph + off);
      bl[tt][kk] = *(const half8*)(Wpl + off);
    }
#pragma unroll
  for (int tt = 0; tt < 2; ++tt)
#pragma unroll
    for (int kk = 0; kk < 4; ++kk) { PIN8(bh[tt][kk]); PIN8(bl[tt][kk]); }
}

// ---- GEMM chunk (r4 form): accf[tt][r] = alpha*XW[n0+lhi*4+r][t(tt,l15)] -----
__device__ __forceinline__ void gemm_chunk(const _Float16* __restrict__ ahp,
                                           const _Float16* __restrict__ alp,
                                           int l,
                                           const half8 (&bh)[2][4],
                                           const half8 (&bl)[2][4],
                                           floatx4 (&accf)[2]) {
  floatx4 z = {0.f, 0.f, 0.f, 0.f};
  accf[0] = z; accf[1] = z;
#pragma unroll
  for (int kk = 0; kk < 4; ++kk) {
    half8 ah = *(const half8*)(ahp + kk * 512 + l * 8);
    half8 al = *(const half8*)(alp + kk * 512 + l * 8);
#pragma unroll
    for (int tt = 0; tt < 2; ++tt) {
      accf[tt] = __builtin_amdgcn_mfma_f32_16x16x32_f16(ah, bh[tt][kk], accf[tt], 0, 0, 0);
      accf[tt] = __builtin_amdgcn_mfma_f32_16x16x32_f16(ah, bl[tt][kk], accf[tt], 0, 0, 0);
      accf[tt] = __builtin_amdgcn_mfma_f32_16x16x32_f16(al, bh[tt][kk], accf[tt], 0, 0, 0);
    }
  }
}

// ---- pass A (r4 form, t-in-lane): sum of (alpha*diff)^2 over segment per t ---
__global__ __launch_bounds__(256, 4)
void k_segsum(const _Float16* __restrict__ Ahp, const _Float16* __restrict__ Alp,
              const float* __restrict__ targets,
              const _Float16* __restrict__ Wph, const _Float16* __restrict__ Wpl,
              float* __restrict__ segsum) {
  int bid = blockIdx.x;
  int seg = bid & 7, tb = (bid >> 3) & 7, b = bid >> 6;   // seg -> XCD
  int tid = threadIdx.x;
  int w = tid >> 6, l = tid & 63;
  int l15 = l & 15, lhi = l >> 4;

  half8 bh[2][4], bl[2][4];
  load_bfrags(Wph, Wpl, tb * 128 + w * 32, l15, lhi, bh, bl);

  int nseg0 = seg * SEGN;
  const _Float16* ahp = Ahp + ((size_t)b * 128 + seg * 16) * 2048;
  const _Float16* alp = Alp + ((size_t)b * 128 + seg * 16) * 2048;
  const float* tgp = targets + (size_t)b * NN + nseg0 + lhi * 4;

  float accs[2] = {0.f, 0.f};
  floatx4 accf[2];
  for (int ch = 0; ch < NCHUNK; ++ch) {
    gemm_chunk(ahp, alp, l, bh, bl, accf);
    floatx4 tg = *(const floatx4*)tgp * ALPHA;
#pragma unroll
    for (int tt = 0; tt < 2; ++tt) {
      float d0 = tg[0] - accf[tt][0], d1 = tg[1] - accf[tt][1];
      float d2 = tg[2] - accf[tt][2], d3 = tg[3] - accf[tt][3];
      accs[tt] += d0 * d0 + d1 * d1 + d2 * d2 + d3 * d3;
    }
    ahp += 2048; alp += 2048; tgp += NC;
  }
#pragma unroll
  for (int tt = 0; tt < 2; ++tt) {
    float tot = accs[tt];
    tot += __shfl_xor(tot, 16);
    tot += __shfl_xor(tot, 32);
    if (lhi == 0)
      segsum[((size_t)b * NT + tb * 128 + w * 32 + tt * 16 + l15) * NSEG + seg] = tot;
  }
}

// ---- tiny exclusive scan over segments per (b,t) -----------------------------
__global__ void k_scan(const float* __restrict__ segsum, float* __restrict__ carry) {
  int idx = blockIdx.x * 256 + threadIdx.x;   // 65536 = NB*NT
  const float* ss = segsum + (size_t)idx * NSEG;
  float* cr = carry + (size_t)idx * NSEG;
  float a = 0.f;
#pragma unroll
  for (int s = 0; s < NSEG; ++s) { cr[s] = a; a += ss[s]; }
}

// ---- pass C (n-in-lane, r5 form): col = n = l15, row = t = lhi*4+r (+tile*16)
__global__ __launch_bounds__(256, 4)
void k_main(const _Float16* __restrict__ Ahp, const _Float16* __restrict__ Alp,
            const float* __restrict__ targets,
            const _Float16* __restrict__ Wph, const _Float16* __restrict__ Wpl,
            const float* __restrict__ carry, floatx4* __restrict__ part) {
  int bid = blockIdx.x;
  int seg = bid & 7, tb = (bid >> 3) & 7, b = bid >> 6;
  int tid = threadIdx.x;
  int w = tid >> 6, l = tid & 63;
  int l15 = l & 15, lhi = l >> 4;
  int tbase = tb * 128 + w * 32;

  half8 wh[2][4], wl[2][4];
#pragma unroll
  for (int tt = 0; tt < 2; ++tt)
#pragma unroll
    for (int kk = 0; kk < 4; ++kk) {
      int t = tbase + tt * 16 + l15;
      int off = t * 128 + kk * 32 + lhi * 8;
      wh[tt][kk] = *(const half8*)(Wph + off);
      wl[tt][kk] = *(const half8*)(Wpl + off);
    }

  float prior2 = (tb < 4) ? LP2_MAJOR : LP2_MINOR;   // t<512 <=> tb<4

  // pcc = prior2 - carry_init (constant); run accumulates this block's chunks
  float pcc[2][4], run[2][4];
#pragma unroll
  for (int tt = 0; tt < 2; ++tt)
#pragma unroll
    for (int r = 0; r < 4; ++r) {
      int t = tbase + tt * 16 + lhi * 4 + r;
      pcc[tt][r] = prior2 - carry[((size_t)b * NT + t) * NSEG + seg];
      run[tt][r] = 0.f;
    }

  int nseg0 = seg * SEGN;
  const _Float16* ahp = Ahp + ((size_t)b * 128 + seg * 16) * 2048;
  const _Float16* alp = Alp + ((size_t)b * 128 + seg * 16) * 2048;
  const float* tgp = targets + (size_t)b * NN + nseg0 + l15;
  size_t pbase = ((size_t)b * NN + nseg0) * 8 + tb;

  __shared__ float sm[4][4][16][5];   // [wave][chunk%4][n_local][{m,s1,s2,pad,pad}]
  floatx4 acc[2];
  for (int ch = 0; ch < NCHUNK; ++ch) {
    // GEMM: acc[tile][r] = alpha*XW[n = n0+l15][t = tbase + tile*16 + lhi*4 + r]
    floatx4 z = {0.f, 0.f, 0.f, 0.f};
    acc[0] = z; acc[1] = z;
#pragma unroll
    for (int kk = 0; kk < 4; ++kk) {
      half8 ah = *(const half8*)(ahp + kk * 512 + l * 8);
      half8 al = *(const half8*)(alp + kk * 512 + l * 8);
#pragma unroll
      for (int tt = 0; tt < 2; ++tt) {
        acc[tt] = __builtin_amdgcn_mfma_f32_16x16x32_f16(wh[tt][kk], ah, acc[tt], 0, 0, 0);
        acc[tt] = __builtin_amdgcn_mfma_f32_16x16x32_f16(wh[tt][kk], al, acc[tt], 0, 0, 0);
        acc[tt] = __builtin_amdgcn_mfma_f32_16x16x32_f16(wl[tt][kk], ah, acc[tt], 0, 0, 0);
      }
    }
    float tgs = tgp[0] * ALPHA;   // this lane's n; broadcast across lhi

    float q[2][4], inc[2][4], lp[2][4];
#pragma unroll
    for (int tt = 0; tt < 2; ++tt)
#pragma unroll
      for (int r = 0; r < 4; ++r) {
        float d = tgs - acc[tt][r];
        q[tt][r] = d * d;
      }
    // inclusive scan over n (l15 within 16-lane row), per t-value
#pragma unroll
    for (int tt = 0; tt < 2; ++tt)
#pragma unroll
      for (int r = 0; r < 4; ++r)
        inc[tt][r] = scan16(q[tt][r]);
    // lp = prior2 - (carry_init + run + exclusive) ; exclusive = inc - q
#pragma unroll
    for (int tt = 0; tt < 2; ++tt)
#pragma unroll
      for (int r = 0; r < 4; ++r) {
        float t1 = pcc[tt][r] - run[tt][r];
        lp[tt][r] = t1 + (q[tt][r] - inc[tt][r]);
      }
    // carry forward: row total = inc @ lane15
#pragma unroll
    for (int tt = 0; tt < 2; ++tt)
#pragma unroll
      for (int r = 0; r < 4; ++r)
        run[tt][r] += bcast15(inc[tt][r]);

    // softmax over this wave's 32 t: in-lane 8 + cross-lane xor16/32
    float m = fmaxf(fmaxf(fmaxf(lp[0][0], lp[0][1]), fmaxf(lp[0][2], lp[0][3])),
                    fmaxf(fmaxf(lp[1][0], lp[1][1]), fmaxf(lp[1][2], lp[1][3])));
    m = fmaxf(m, __shfl_xor(m, 16));
    m = fmaxf(m, __shfl_xor(m, 32));
    float s1 = 0.f, s2 = 0.f;
#pragma unroll
    for (int tt = 0; tt < 2; ++tt)
#pragma unroll
      for (int r = 0; r < 4; ++r) {
        float e = fexp2(lp[tt][r] - m);
        s1 += e;
        s2 = fmaf(e, acc[tt][r], s2);
      }
    s1 += __shfl_xor(s1, 16);
    s1 += __shfl_xor(s1, 32);
    s2 += __shfl_xor(s2, 16);
    s2 += __shfl_xor(s2, 32);

    if (l < 16) {
      sm[w][ch & 3][l15][0] = m;
      sm[w][ch & 3][l15][1] = s1;
      sm[w][ch & 3][l15][2] = s2;
    }
    if ((ch & 3) == 3) {               // merge 4 chunks' partials across waves
      __syncthreads();
      if (tid < 64) {
        int c4 = tid >> 4, row = tid & 15;
        float m0 = sm[0][c4][row][0], m1 = sm[1][c4][row][0];
        float m2 = sm[2][c4][row][0], m3 = sm[3][c4][row][0];
        float M = fmaxf(fmaxf(m0, m1), fmaxf(m2, m3));
        float e0 = fexp2(m0 - M), e1 = fexp2(m1 - M);
        float e2 = fexp2(m2 - M), e3 = fexp2(m3 - M);
        float S1 = sm[0][c4][row][1] * e0 + sm[1][c4][row][1] * e1 +
                   sm[2][c4][row][1] * e2 + sm[3][c4][row][1] * e3;
        float S2 = sm[0][c4][row][2] * e0 + sm[1][c4][row][2] * e1 +
                   sm[2][c4][row][2] * e2 + sm[3][c4][row][2] * e3;
        floatx4 v;
        v[0] = M; v[1] = S1; v[2] = S2; v[3] = 0.f;
        part[pbase + (size_t)((ch - 3 + c4) * 16 + row) * 8] = v;
      }
      __syncthreads();
    }
    ahp += 2048; alp += 2048; tgp += NC;
  }
}

// ---- combine 8 tb-partials per (b,n) -----------------------------------------
__global__ void k_combine(const floatx4* __restrict__ part, float* __restrict__ out) {
  int idx = blockIdx.x * 256 + threadIdx.x;   // 131072 = NB*NN
  const floatx4* p = part + (size_t)idx * 8;
  floatx4 v[8];
  float M = -3.4e38f;
#pragma unroll
  for (int j = 0; j < 8; ++j) { v[j] = p[j]; M = fmaxf(M, v[j][0]); }
  float s1 = 0.f, s2 = 0.f;
#pragma unroll
  for (int j = 0; j < 8; ++j) {
    float e = fexp2(v[j][0] - M);
    s1 += v[j][1] * e;
    s2 += v[j][2] * e;
  }
  out[idx] = s2 / s1 * INV_ALPHA;   // undo alpha scale on XW values
}

extern "C" void kernel_launch(void* const* d_in, const int* in_sizes, int n_in,
                              void* d_out, int out_size, void* d_ws, size_t ws_size,
                              hipStream_t stream) {
  const float* data    = (const float*)d_in[0];
  const float* targets = (const float*)d_in[1];
  const float* W       = (const float*)d_in[2];
  const float* Wm      = (const float*)d_in[3];
  float* out = (float*)d_out;

  char* ws = (char*)d_ws;
  const size_t MB = 1u << 20;
  _Float16* Wph  = (_Float16*)ws;                          // 256 KB
  _Float16* Wpl  = (_Float16*)(ws + 256 * 1024);           // 256 KB
  _Float16* Ahp  = (_Float16*)(ws + 512 * 1024);           // 32 MB
  _Float16* Alp  = (_Float16*)(ws + 512 * 1024 + 32 * MB); // 32 MB
  float* segsum  = (float*)(ws + 512 * 1024 + 64 * MB);    // 2 MB
  float* carry   = (float*)(ws + 512 * 1024 + 66 * MB);    // 2 MB
  floatx4* part  = (floatx4*)(ws + 512 * 1024 + 68 * MB);  // 16 MB

  k_prep<<<512, 256, 0, stream>>>(W, Wm, Wph, Wpl);
  k_prep_data<<<8192, 256, 0, stream>>>(data, Ahp, Alp);
  k_segsum<<<NB * NSEG * 8, 256, 0, stream>>>(Ahp, Alp, targets, Wph, Wpl, segsum);
  k_scan<<<(NB * NT) / 256, 256, 0, stream>>>(segsum, carry);
  k_main<<<NB * NSEG * 8, 256, 0, stream>>>(Ahp, Alp, targets, Wph, Wpl, carry, part);
  k_combine<<<(NB * NN) / 256, 256, 0, stream>>>(part, out);
}

// Round 8
// 258.502 us; speedup vs baseline: 1.7861x; 1.0825x over previous
//
#include <hip/hip_runtime.h>

typedef _Float16 half8 __attribute__((ext_vector_type(8)));
typedef float floatx4 __attribute__((ext_vector_type(4)));

#define NB 64
#define NN 2048
#define ND 128
#define NT 1024
#define NC 16           // n-rows per chunk
#define NCHUNKS 128     // NN / NC (full sweep per block)

// exp2-domain constants: alpha^2 = 0.5*log2(e); scaling W,targets by alpha
// makes (alpha*d)^2 sums directly usable as log2 exponents.
#define ALPHA 0.84932184f
#define INV_ALPHA 1.17741002f
#define LP2_MAJOR (-1.7369655941662063f)   // log2(0.9/3)
#define LP2_MINOR (-12.321928094887362f)   // log2(0.1/512)

// bare v_exp_f32 (input already in log2 units, always <= 0 here)
__device__ __forceinline__ float fexp2(float x) {
  float r;
  asm("v_exp_f32 %0, %1" : "=v"(r) : "v"(x));
  return r;
}

// keep-alive pin (r4-proven form: once, immediately after the loads)
#define PIN8(x) asm volatile("" : "+v"(x))

// DPP row_shr add step for 16-lane inclusive scan (zero-fill at row edge)
template <int CTRL>
__device__ __forceinline__ float dppshr_add(float x) {
  int i = __builtin_bit_cast(int, x);
  int s = __builtin_amdgcn_update_dpp(0, i, CTRL, 0xF, 0xF, true);
  return x + __builtin_bit_cast(float, s);
}
// inclusive scan over l15 within each 16-lane row
__device__ __forceinline__ float scan16(float x) {
  x = dppshr_add<0x111>(x);   // row_shr:1
  x = dppshr_add<0x112>(x);   // row_shr:2
  x = dppshr_add<0x114>(x);   // row_shr:4
  x = dppshr_add<0x118>(x);   // row_shr:8
  return x;
}
// broadcast row-lane-15 value to all 16 lanes of the row
__device__ __forceinline__ float bcast15(float x) {
  int i = __builtin_bit_cast(int, x);
  i = __builtin_amdgcn_ds_swizzle(i, 0x1F0);
  return __builtin_bit_cast(float, i);
}

// ---- prep: W_all (f32, [D][T]) -> alpha-scaled t-major f16 hi/lo [t][d] ------
__global__ void k_prep(const float* __restrict__ W, const float* __restrict__ Wm,
                       _Float16* __restrict__ Wph, _Float16* __restrict__ Wpl) {
  int idx = blockIdx.x * 256 + threadIdx.x;      // 131072 = 1024*128
  int t = idx >> 7, d = idx & 127;
  float x = (t < 512) ? W[d * 512 + t] : Wm[d * 512 + (t - 512)];
  x *= ALPHA;
  _Float16 h = (_Float16)x;
  _Float16 l = (_Float16)(x - (float)h);
  Wph[idx] = h;
  Wpl[idx] = l;
}

// ---- prep: data (f32 [B][N][D]) -> fragment-packed f16 hi/lo -----------------
__global__ void k_prep_data(const float* __restrict__ data,
                            _Float16* __restrict__ Ahp, _Float16* __restrict__ Alp) {
  int idx = blockIdx.x * 256 + threadIdx.x;      // 2,097,152 threads
  int l = idx & 63, kk = (idx >> 6) & 3, ch = (idx >> 8) & 127, b = idx >> 15;
  int row = ch * 16 + (l & 15);
  int dcol = kk * 32 + (l >> 4) * 8;
  const float* src = data + ((size_t)b * NN + row) * ND + dcol;
  floatx4 a0 = *(const floatx4*)src;
  floatx4 a1 = *(const floatx4*)(src + 4);
  half8 h, lo;
#pragma unroll
  for (int j = 0; j < 4; ++j) {
    h[j] = (_Float16)a0[j];
    lo[j] = (_Float16)(a0[j] - (float)h[j]);
    h[4 + j] = (_Float16)a1[j];
    lo[4 + j] = (_Float16)(a1[j] - (float)h[4 + j]);
  }
  size_t o = (size_t)idx * 8;
  *(half8*)(Ahp + o) = h;
  *(half8*)(Alp + o) = lo;
}

// ---- fused single pass: block = (b, tb); 8 waves x 16 t; streams all 2048 n --
// n-in-lane: acc[r] = alpha*XW[n = ch*16 + l15][t = tb*128 + w*16 + lhi*4 + r]
__global__ __launch_bounds__(512, 4)
void k_fused(const _Float16* __restrict__ Ahp, const _Float16* __restrict__ Alp,
             const float* __restrict__ targets,
             const _Float16* __restrict__ Wph, const _Float16* __restrict__ Wpl,
             floatx4* __restrict__ part) {
  int bid = blockIdx.x;
  int tb = bid & 7, b = bid >> 3;
  int tid = threadIdx.x;
  int w = tid >> 6, l = tid & 63;
  int l15 = l & 15, lhi = l >> 4;
  int wavebase = tb * 128 + w * 16;

  // W fragments for this wave's 16 t (A-operand role): 32 VGPRs
  half8 wh[4], wl[4];
#pragma unroll
  for (int kk = 0; kk < 4; ++kk) {
    int off = (wavebase + l15) * 128 + kk * 32 + lhi * 8;
    wh[kk] = *(const half8*)(Wph + off);
    wl[kk] = *(const half8*)(Wpl + off);
  }
#pragma unroll
  for (int kk = 0; kk < 4; ++kk) { PIN8(wh[kk]); PIN8(wl[kk]); }

  float prior2 = (tb < 4) ? LP2_MAJOR : LP2_MINOR;   // t<512 <=> tb<4
  float run[4] = {0.f, 0.f, 0.f, 0.f};               // n-prefix per t (in regs!)

  const _Float16* ahp = Ahp + (size_t)b * 128 * 2048;
  const _Float16* alp = Alp + (size_t)b * 128 * 2048;
  const float* tgp = targets + (size_t)b * NN + l15;
  size_t pbase = (size_t)b * NN * 8 + tb;

  __shared__ float sm[8][4][16][5];   // [wave][chunk%4][n_local][{m,s1,s2,pad,pad}]

  for (int ch = 0; ch < NCHUNKS; ++ch) {
    floatx4 acc = {0.f, 0.f, 0.f, 0.f};
#pragma unroll
    for (int kk = 0; kk < 4; ++kk) {
      half8 ah = *(const half8*)(ahp + kk * 512 + l * 8);
      half8 al = *(const half8*)(alp + kk * 512 + l * 8);
      acc = __builtin_amdgcn_mfma_f32_16x16x32_f16(wh[kk], ah, acc, 0, 0, 0);
      acc = __builtin_amdgcn_mfma_f32_16x16x32_f16(wh[kk], al, acc, 0, 0, 0);
      acc = __builtin_amdgcn_mfma_f32_16x16x32_f16(wl[kk], ah, acc, 0, 0, 0);
    }
    float tgs = tgp[0] * ALPHA;   // this lane's n

    float q[4], inc[4], lp[4];
#pragma unroll
    for (int r = 0; r < 4; ++r) {
      float d = tgs - acc[r];
      q[r] = d * d;
    }
#pragma unroll
    for (int r = 0; r < 4; ++r)
      inc[r] = scan16(q[r]);       // inclusive n-prefix within chunk, per t
#pragma unroll
    for (int r = 0; r < 4; ++r) {
      float t1 = (prior2 - run[r]);
      lp[r] = t1 + (q[r] - inc[r]);   // exclusive prefix
    }
#pragma unroll
    for (int r = 0; r < 4; ++r)
      run[r] += bcast15(inc[r]);   // carry chunk total forward

    // softmax partial over this wave's 16 t: in-lane 4 + cross-lhi xor16/32
    float m = fmaxf(fmaxf(lp[0], lp[1]), fmaxf(lp[2], lp[3]));
    m = fmaxf(m, __shfl_xor(m, 16));
    m = fmaxf(m, __shfl_xor(m, 32));
    float s1 = 0.f, s2 = 0.f;
#pragma unroll
    for (int r = 0; r < 4; ++r) {
      float e = fexp2(lp[r] - m);
      s1 += e;
      s2 = fmaf(e, acc[r], s2);
    }
    s1 += __shfl_xor(s1, 16);
    s1 += __shfl_xor(s1, 32);
    s2 += __shfl_xor(s2, 16);
    s2 += __shfl_xor(s2, 32);

    if (l < 16) {
      sm[w][ch & 3][l15][0] = m;
      sm[w][ch & 3][l15][1] = s1;
      sm[w][ch & 3][l15][2] = s2;
    }
    if ((ch & 3) == 3) {               // merge 4 chunks' partials across 8 waves
      __syncthreads();
      if (tid < 64) {
        int c4 = tid >> 4, row = tid & 15;
        float mw[8];
#pragma unroll
        for (int wv = 0; wv < 8; ++wv) mw[wv] = sm[wv][c4][row][0];
        float M = mw[0];
#pragma unroll
        for (int wv = 1; wv < 8; ++wv) M = fmaxf(M, mw[wv]);
        float S1 = 0.f, S2 = 0.f;
#pragma unroll
        for (int wv = 0; wv < 8; ++wv) {
          float e = fexp2(mw[wv] - M);
          S1 = fmaf(sm[wv][c4][row][1], e, S1);
          S2 = fmaf(sm[wv][c4][row][2], e, S2);
        }
        floatx4 v;
        v[0] = M; v[1] = S1; v[2] = S2; v[3] = 0.f;
        part[pbase + (size_t)((ch - 3 + c4) * 16 + row) * 8] = v;
      }
      __syncthreads();
    }
    ahp += 2048; alp += 2048; tgp += NC;
  }
}

// ---- combine 8 tb-partials per (b,n) -----------------------------------------
__global__ void k_combine(const floatx4* __restrict__ part, float* __restrict__ out) {
  int idx = blockIdx.x * 256 + threadIdx.x;   // 131072 = NB*NN
  const floatx4* p = part + (size_t)idx * 8;
  floatx4 v[8];
  float M = -3.4e38f;
#pragma unroll
  for (int j = 0; j < 8; ++j) { v[j] = p[j]; M = fmaxf(M, v[j][0]); }
  float s1 = 0.f, s2 = 0.f;
#pragma unroll
  for (int j = 0; j < 8; ++j) {
    float e = fexp2(v[j][0] - M);
    s1 += v[j][1] * e;
    s2 += v[j][2] * e;
  }
  out[idx] = s2 / s1 * INV_ALPHA;   // undo alpha scale on XW values
}

extern "C" void kernel_launch(void* const* d_in, const int* in_sizes, int n_in,
                              void* d_out, int out_size, void* d_ws, size_t ws_size,
                              hipStream_t stream) {
  const float* data    = (const float*)d_in[0];
  const float* targets = (const float*)d_in[1];
  const float* W       = (const float*)d_in[2];
  const float* Wm      = (const float*)d_in[3];
  float* out = (float*)d_out;

  char* ws = (char*)d_ws;
  const size_t MB = 1u << 20;
  _Float16* Wph  = (_Float16*)ws;                          // 256 KB
  _Float16* Wpl  = (_Float16*)(ws + 256 * 1024);           // 256 KB
  _Float16* Ahp  = (_Float16*)(ws + 512 * 1024);           // 32 MB
  _Float16* Alp  = (_Float16*)(ws + 512 * 1024 + 32 * MB); // 32 MB
  floatx4* part  = (floatx4*)(ws + 512 * 1024 + 64 * MB);  // 16 MB

  k_prep<<<512, 256, 0, stream>>>(W, Wm, Wph, Wpl);
  k_prep_data<<<8192, 256, 0, stream>>>(data, Ahp, Alp);
  k_fused<<<NB * 8, 512, 0, stream>>>(Ahp, Alp, targets, Wph, Wpl, part);
  k_combine<<<(NB * NN) / 256, 256, 0, stream>>>(part, out);
}

// Round 9
// 234.067 us; speedup vs baseline: 1.9725x; 1.1044x over previous
//
#include <hip/hip_runtime.h>

typedef _Float16 half8 __attribute__((ext_vector_type(8)));
typedef float floatx4 __attribute__((ext_vector_type(4)));

#define NB 64
#define NN 2048
#define ND 128
#define NT 1024
#define NC 16           // n-rows per chunk
#define NCHUNKS 128     // NN / NC (full sweep per block)

// exp2-domain constants: alpha^2 = 0.5*log2(e); scaling W,targets by alpha
// makes (alpha*d)^2 sums directly usable as log2 exponents.
#define ALPHA 0.84932184f
#define INV_ALPHA 1.17741002f
#define LP2_MAJOR (-1.7369655941662063f)   // log2(0.9/3)
#define LP2_MINOR (-12.321928094887362f)   // log2(0.1/512)

// bare v_exp_f32 (input already in log2 units, always <= 0 here)
__device__ __forceinline__ float fexp2(float x) {
  float r;
  asm("v_exp_f32 %0, %1" : "=v"(r) : "v"(x));
  return r;
}

// keep-alive pin (r4-proven form: once, immediately after the loads)
#define PIN8(x) asm volatile("" : "+v"(x))

// DPP row_shr add step for 16-lane inclusive scan (zero-fill at row edge)
template <int CTRL>
__device__ __forceinline__ float dppshr_add(float x) {
  int i = __builtin_bit_cast(int, x);
  int s = __builtin_amdgcn_update_dpp(0, i, CTRL, 0xF, 0xF, true);
  return x + __builtin_bit_cast(float, s);
}
// inclusive scan over l15 within each 16-lane row
__device__ __forceinline__ float scan16(float x) {
  x = dppshr_add<0x111>(x);   // row_shr:1
  x = dppshr_add<0x112>(x);   // row_shr:2
  x = dppshr_add<0x114>(x);   // row_shr:4
  x = dppshr_add<0x118>(x);   // row_shr:8
  return x;
}
// broadcast row-lane-15 value to all 16 lanes of the row
__device__ __forceinline__ float bcast15(float x) {
  int i = __builtin_bit_cast(int, x);
  i = __builtin_amdgcn_ds_swizzle(i, 0x1F0);
  return __builtin_bit_cast(float, i);
}

// ---- prep: W_all (f32, [D][T]) -> alpha-scaled t-major f16 hi/lo [t][d] ------
__global__ void k_prep(const float* __restrict__ W, const float* __restrict__ Wm,
                       _Float16* __restrict__ Wph, _Float16* __restrict__ Wpl) {
  int idx = blockIdx.x * 256 + threadIdx.x;      // 131072 = 1024*128
  int t = idx >> 7, d = idx & 127;
  float x = (t < 512) ? W[d * 512 + t] : Wm[d * 512 + (t - 512)];
  x *= ALPHA;
  _Float16 h = (_Float16)x;
  _Float16 l = (_Float16)(x - (float)h);
  Wph[idx] = h;
  Wpl[idx] = l;
}

// ---- prep: data (f32 [B][N][D]) -> fragment-packed f16 hi/lo -----------------
__global__ void k_prep_data(const float* __restrict__ data,
                            _Float16* __restrict__ Ahp, _Float16* __restrict__ Alp) {
  int idx = blockIdx.x * 256 + threadIdx.x;      // 2,097,152 threads
  int l = idx & 63, kk = (idx >> 6) & 3, ch = (idx >> 8) & 127, b = idx >> 15;
  int row = ch * 16 + (l & 15);
  int dcol = kk * 32 + (l >> 4) * 8;
  const float* src = data + ((size_t)b * NN + row) * ND + dcol;
  floatx4 a0 = *(const floatx4*)src;
  floatx4 a1 = *(const floatx4*)(src + 4);
  half8 h, lo;
#pragma unroll
  for (int j = 0; j < 4; ++j) {
    h[j] = (_Float16)a0[j];
    lo[j] = (_Float16)(a0[j] - (float)h[j]);
    h[4 + j] = (_Float16)a1[j];
    lo[4 + j] = (_Float16)(a1[j] - (float)h[4 + j]);
  }
  size_t o = (size_t)idx * 8;
  *(half8*)(Ahp + o) = h;
  *(half8*)(Alp + o) = lo;
}

// ---- fused single pass: block = (b, tq); 8 waves x 16 t; streams all 2048 n --
// n-in-lane: acc[r] = alpha*XW[n = ch*16 + l15][t = tq*128 + w*16 + lhi*4 + r]
__global__ __launch_bounds__(512, 4)
void k_fused(const _Float16* __restrict__ Ahp, const _Float16* __restrict__ Alp,
             const float* __restrict__ targets,
             const _Float16* __restrict__ Wph, const _Float16* __restrict__ Wpl,
             floatx4* __restrict__ part) {
  int bid = blockIdx.x;
  // XCD-affinity: all 8 tq-partners of one b share bid%8 -> same XCD L2
  int xcd = bid & 7, rest = bid >> 3;
  int tq = rest & 7, b = (rest >> 3) * 8 + xcd;
  int tid = threadIdx.x;
  int w = tid >> 6, l = tid & 63;
  int l15 = l & 15, lhi = l >> 4;
  int wavebase = tq * 128 + w * 16;

  // W fragments for this wave's 16 t (A-operand role): 32 VGPRs
  half8 wh[4], wl[4];
#pragma unroll
  for (int kk = 0; kk < 4; ++kk) {
    int off = (wavebase + l15) * 128 + kk * 32 + lhi * 8;
    wh[kk] = *(const half8*)(Wph + off);
    wl[kk] = *(const half8*)(Wpl + off);
  }
#pragma unroll
  for (int kk = 0; kk < 4; ++kk) { PIN8(wh[kk]); PIN8(wl[kk]); }

  float prior2 = (tq < 4) ? LP2_MAJOR : LP2_MINOR;   // t<512 <=> tq<4
  float run[4] = {0.f, 0.f, 0.f, 0.f};               // n-prefix per t (in regs)

  // wave-uniform bases; per-lane offset folded into the load index (saddr form)
  const _Float16* ahp = Ahp + (size_t)b * 128 * 2048;
  const _Float16* alp = Alp + (size_t)b * 128 * 2048;
  const float* tgp = targets + (size_t)b * NN + l15;
  size_t pbase = (size_t)b * NN * 8 + tq;
  int lo8 = l * 8;

  __shared__ float sm[8][8][16][5];   // [wave][chunk%8][n_local][{m,s1,s2,pad,pad}]

#define LOADA(AH, AL, CHOFF)                                          \
  do {                                                                \
    _Pragma("unroll")                                                 \
    for (int kk = 0; kk < 4; ++kk) {                                  \
      AH[kk] = *(const half8*)(ahp + (CHOFF) * 2048 + kk * 512 + lo8);\
      AL[kk] = *(const half8*)(alp + (CHOFF) * 2048 + kk * 512 + lo8);\
    }                                                                 \
  } while (0)

#define GEMM(ACC, AH, AL)                                                      \
  do {                                                                         \
    _Pragma("unroll")                                                          \
    for (int kk = 0; kk < 4; ++kk) {                                           \
      ACC = __builtin_amdgcn_mfma_f32_16x16x32_f16(wh[kk], AH[kk], ACC, 0, 0, 0); \
      ACC = __builtin_amdgcn_mfma_f32_16x16x32_f16(wh[kk], AL[kk], ACC, 0, 0, 0); \
      ACC = __builtin_amdgcn_mfma_f32_16x16x32_f16(wl[kk], AH[kk], ACC, 0, 0, 0); \
    }                                                                          \
  } while (0)

#define EPI(ACC, SLOT, TGOFF)                                         \
  do {                                                                \
    float tgs = tgp[TGOFF] * ALPHA;                                   \
    float q[4], inc[4], lp[4];                                        \
    _Pragma("unroll")                                                 \
    for (int r = 0; r < 4; ++r) {                                     \
      float d = tgs - ACC[r];                                         \
      q[r] = d * d;                                                   \
    }                                                                 \
    _Pragma("unroll")                                                 \
    for (int r = 0; r < 4; ++r) inc[r] = scan16(q[r]);                \
    _Pragma("unroll")                                                 \
    for (int r = 0; r < 4; ++r)                                       \
      lp[r] = (prior2 - run[r]) + (q[r] - inc[r]);                    \
    _Pragma("unroll")                                                 \
    for (int r = 0; r < 4; ++r) run[r] += bcast15(inc[r]);            \
    float m = fmaxf(fmaxf(lp[0], lp[1]), fmaxf(lp[2], lp[3]));        \
    m = fmaxf(m, __shfl_xor(m, 16));                                  \
    m = fmaxf(m, __shfl_xor(m, 32));                                  \
    float s1 = 0.f, s2 = 0.f;                                         \
    _Pragma("unroll")                                                 \
    for (int r = 0; r < 4; ++r) {                                     \
      float e = fexp2(lp[r] - m);                                     \
      s1 += e;                                                        \
      s2 = fmaf(e, ACC[r], s2);                                       \
    }                                                                 \
    s1 += __shfl_xor(s1, 16);                                         \
    s1 += __shfl_xor(s1, 32);                                         \
    s2 += __shfl_xor(s2, 16);                                         \
    s2 += __shfl_xor(s2, 32);                                         \
    if (l < 16) {                                                     \
      sm[w][SLOT][l15][0] = m;                                        \
      sm[w][SLOT][l15][1] = s1;                                       \
      sm[w][SLOT][l15][2] = s2;                                       \
    }                                                                 \
  } while (0)

  half8 a0h[4], a0l[4], a1h[4], a1l[4];
  LOADA(a0h, a0l, 0);   // prime chunk 0

  for (int ch = 0; ch < NCHUNKS; ch += 2) {
    LOADA(a1h, a1l, 1);               // issue ch+1 loads before any compute
    floatx4 acc0 = {0.f, 0.f, 0.f, 0.f};
    GEMM(acc0, a0h, a0l);             // consumes a0 (in flight since last iter)
    LOADA(a0h, a0l, 2);               // issue ch+2 loads (overrun on last iter
                                      //  lands in Alp/part regions: in-ws, unused)
    EPI(acc0, (ch & 7), 0);
    floatx4 acc1 = {0.f, 0.f, 0.f, 0.f};
    GEMM(acc1, a1h, a1l);
    EPI(acc1, ((ch + 1) & 7), 16);

    if ((ch & 7) == 6) {              // merge 8 chunks' partials across 8 waves
      __syncthreads();
      if (tid < 128) {
        int c = tid >> 4, row = tid & 15;
        float M = sm[0][c][row][0];
#pragma unroll
        for (int wv = 1; wv < 8; ++wv) M = fmaxf(M, sm[wv][c][row][0]);
        float S1 = 0.f, S2 = 0.f;
#pragma unroll
        for (int wv = 0; wv < 8; ++wv) {
          float e = fexp2(sm[wv][c][row][0] - M);
          S1 = fmaf(sm[wv][c][row][1], e, S1);
          S2 = fmaf(sm[wv][c][row][2], e, S2);
        }
        floatx4 v;
        v[0] = M; v[1] = S1; v[2] = S2; v[3] = 0.f;
        part[pbase + (size_t)((ch - 6 + c) * 16 + row) * 8] = v;
      }
      __syncthreads();
    }
    ahp += 4096; alp += 4096; tgp += 32;
  }
#undef LOADA
#undef GEMM
#undef EPI
}

// ---- combine 8 tq-partials per (b,n) -----------------------------------------
__global__ void k_combine(const floatx4* __restrict__ part, float* __restrict__ out) {
  int idx = blockIdx.x * 256 + threadIdx.x;   // 131072 = NB*NN
  const floatx4* p = part + (size_t)idx * 8;
  floatx4 v[8];
  float M = -3.4e38f;
#pragma unroll
  for (int j = 0; j < 8; ++j) { v[j] = p[j]; M = fmaxf(M, v[j][0]); }
  float s1 = 0.f, s2 = 0.f;
#pragma unroll
  for (int j = 0; j < 8; ++j) {
    float e = fexp2(v[j][0] - M);
    s1 += v[j][1] * e;
    s2 += v[j][2] * e;
  }
  out[idx] = s2 / s1 * INV_ALPHA;   // undo alpha scale on XW values
}

extern "C" void kernel_launch(void* const* d_in, const int* in_sizes, int n_in,
                              void* d_out, int out_size, void* d_ws, size_t ws_size,
                              hipStream_t stream) {
  const float* data    = (const float*)d_in[0];
  const float* targets = (const float*)d_in[1];
  const float* W       = (const float*)d_in[2];
  const float* Wm      = (const float*)d_in[3];
  float* out = (float*)d_out;

  char* ws = (char*)d_ws;
  const size_t MB = 1u << 20;
  _Float16* Wph  = (_Float16*)ws;                          // 256 KB
  _Float16* Wpl  = (_Float16*)(ws + 256 * 1024);           // 256 KB
  _Float16* Ahp  = (_Float16*)(ws + 512 * 1024);           // 32 MB
  _Float16* Alp  = (_Float16*)(ws + 512 * 1024 + 32 * MB); // 32 MB
  floatx4* part  = (floatx4*)(ws + 512 * 1024 + 64 * MB);  // 16 MB

  k_prep<<<512, 256, 0, stream>>>(W, Wm, Wph, Wpl);
  k_prep_data<<<8192, 256, 0, stream>>>(data, Ahp, Alp);
  k_fused<<<NB * 8, 512, 0, stream>>>(Ahp, Alp, targets, Wph, Wpl, part);
  k_combine<<<(NB * NN) / 256, 256, 0, stream>>>(part, out);
}

// Round 10
// 195.381 us; speedup vs baseline: 2.3631x; 1.1980x over previous
//
#include <hip/hip_runtime.h>

typedef _Float16 half8 __attribute__((ext_vector_type(8)));
typedef float floatx4 __attribute__((ext_vector_type(4)));

#define NB 64
#define NN 2048
#define ND 128
#define NT 1024
#define NC 16           // n-rows per chunk
#define NCHUNKS 128     // NN / NC (full sweep per block)

// exp2-domain constants: alpha^2 = 0.5*log2(e); scaling W,targets by alpha
// makes (alpha*d)^2 sums directly usable as log2 exponents.
#define ALPHA 0.84932184f
#define INV_ALPHA 1.17741002f
#define LP2_MAJOR (-1.7369655941662063f)   // log2(0.9/3)
#define LP2_MINOR (-12.321928094887362f)   // log2(0.1/512)

// bare v_exp_f32 (input already in log2 units, always <= 0 here)
__device__ __forceinline__ float fexp2(float x) {
  float r;
  asm("v_exp_f32 %0, %1" : "=v"(r) : "v"(x));
  return r;
}

// keep-alive pin (r4-proven form: once, immediately after the loads)
#define PIN8(x) asm volatile("" : "+v"(x))

// DPP row_shr add step for 16-lane inclusive scan (zero-fill at row edge)
template <int CTRL>
__device__ __forceinline__ float dppshr_add(float x) {
  int i = __builtin_bit_cast(int, x);
  int s = __builtin_amdgcn_update_dpp(0, i, CTRL, 0xF, 0xF, true);
  return x + __builtin_bit_cast(float, s);
}
// inclusive scan over l15 within each 16-lane row
__device__ __forceinline__ float scan16(float x) {
  x = dppshr_add<0x111>(x);   // row_shr:1
  x = dppshr_add<0x112>(x);   // row_shr:2
  x = dppshr_add<0x114>(x);   // row_shr:4
  x = dppshr_add<0x118>(x);   // row_shr:8
  return x;
}
// broadcast row-lane-15 value to all 16 lanes of the row
__device__ __forceinline__ float bcast15(float x) {
  int i = __builtin_bit_cast(int, x);
  i = __builtin_amdgcn_ds_swizzle(i, 0x1F0);
  return __builtin_bit_cast(float, i);
}

// ---- prep: W_all (f32, [D][T]) -> alpha-scaled t-major f16 hi/lo [t][d] ------
__global__ void k_prep(const float* __restrict__ W, const float* __restrict__ Wm,
                       _Float16* __restrict__ Wph, _Float16* __restrict__ Wpl) {
  int idx = blockIdx.x * 256 + threadIdx.x;      // 131072 = 1024*128
  int t = idx >> 7, d = idx & 127;
  float x = (t < 512) ? W[d * 512 + t] : Wm[d * 512 + (t - 512)];
  x *= ALPHA;
  _Float16 h = (_Float16)x;
  _Float16 l = (_Float16)(x - (float)h);
  Wph[idx] = h;
  Wpl[idx] = l;
}

// ---- prep: data -> per-chunk packed [chunk: hi 2048h | lo 2048h] -------------
__global__ void k_prep_data(const float* __restrict__ data,
                            _Float16* __restrict__ Apk) {
  int idx = blockIdx.x * 256 + threadIdx.x;      // 2,097,152 threads
  int l = idx & 63, kk = (idx >> 6) & 3, ch = (idx >> 8) & 127, b = idx >> 15;
  int row = ch * 16 + (l & 15);
  int dcol = kk * 32 + (l >> 4) * 8;
  const float* src = data + ((size_t)b * NN + row) * ND + dcol;
  floatx4 a0 = *(const floatx4*)src;
  floatx4 a1 = *(const floatx4*)(src + 4);
  half8 h, lo;
#pragma unroll
  for (int j = 0; j < 4; ++j) {
    h[j] = (_Float16)a0[j];
    lo[j] = (_Float16)(a0[j] - (float)h[j]);
    h[4 + j] = (_Float16)a1[j];
    lo[4 + j] = (_Float16)(a1[j] - (float)h[4 + j]);
  }
  size_t o = ((size_t)(b * 128 + ch)) * 4096 + kk * 512 + l * 8;
  *(half8*)(Apk + o) = h;            // hi half of chunk block
  *(half8*)(Apk + o + 2048) = lo;    // lo half of chunk block
}

// ---- fused single pass: block = (b, tq); 8 waves x 16 t; streams all 2048 n --
// A staged via LDS (dbuf): each wave global-loads ONE 16B slice per chunk,
// ds_writes it; all waves ds_read their MFMA fragments from LDS.
__global__ __launch_bounds__(512, 4)
void k_fused(const _Float16* __restrict__ Apk, const float* __restrict__ targets,
             const _Float16* __restrict__ Wph, const _Float16* __restrict__ Wpl,
             floatx4* __restrict__ part) {
  int bid = blockIdx.x;
  // XCD-affinity: all 8 tq-partners of one b share bid%8 -> same XCD L2
  int xcd = bid & 7, rest = bid >> 3;
  int tq = rest & 7, b = (rest >> 3) * 8 + xcd;
  int tid = threadIdx.x;
  int w = tid >> 6, l = tid & 63;
  int l15 = l & 15, lhi = l >> 4;
  int wavebase = tq * 128 + w * 16;

  // W fragments for this wave's 16 t (A-operand role): 32 VGPRs
  half8 wh[4], wl[4];
#pragma unroll
  for (int kk = 0; kk < 4; ++kk) {
    int off = (wavebase + l15) * 128 + kk * 32 + lhi * 8;
    wh[kk] = *(const half8*)(Wph + off);
    wl[kk] = *(const half8*)(Wpl + off);
  }
#pragma unroll
  for (int kk = 0; kk < 4; ++kk) { PIN8(wh[kk]); PIN8(wl[kk]); }

  float prior2 = (tq < 4) ? LP2_MAJOR : LP2_MINOR;   // t<512 <=> tq<4
  float run[4] = {0.f, 0.f, 0.f, 0.f};               // n-prefix per t (in regs)

  const _Float16* abase = Apk + (size_t)b * 128 * 4096;
  const float* tgp = targets + (size_t)b * NN + l15;
  size_t pbase = (size_t)b * NN * 8 + tq;

  __shared__ _Float16 Abuf[2][4096];        // 2 x 8 KB chunk buffers
  __shared__ float sm[8][4][4][16][4];      // [wave][slot][lhi][n][{m,s1,s2,pad}]

  int wslot = w * 512 + l * 8;              // this thread's 16B slice (halfs)

  // prologue: stage chunk 0, prefetch chunk 1 into regs
  half8 stg = *(const half8*)(abase + wslot);
  *(half8*)&Abuf[0][wslot] = stg;
  stg = *(const half8*)(abase + 4096 + wslot);
  __syncthreads();

  for (int ch = 0; ch < NCHUNKS; ++ch) {
    int cur = ch & 1;
    // fragments from LDS (same data for all waves)
    half8 ah[4], al[4];
#pragma unroll
    for (int kk = 0; kk < 4; ++kk) {
      ah[kk] = *(const half8*)&Abuf[cur][kk * 512 + l * 8];
      al[kk] = *(const half8*)&Abuf[cur][2048 + kk * 512 + l * 8];
    }
    floatx4 acc = {0.f, 0.f, 0.f, 0.f};
#pragma unroll
    for (int kk = 0; kk < 4; ++kk) {
      acc = __builtin_amdgcn_mfma_f32_16x16x32_f16(wh[kk], ah[kk], acc, 0, 0, 0);
      acc = __builtin_amdgcn_mfma_f32_16x16x32_f16(wh[kk], al[kk], acc, 0, 0, 0);
      acc = __builtin_amdgcn_mfma_f32_16x16x32_f16(wl[kk], ah[kk], acc, 0, 0, 0);
    }
    float tgs = tgp[0] * ALPHA;   // this lane's n

    float q[4], inc[4], lp[4];
#pragma unroll
    for (int r = 0; r < 4; ++r) {
      float d = tgs - acc[r];
      q[r] = d * d;
    }
#pragma unroll
    for (int r = 0; r < 4; ++r)
      inc[r] = scan16(q[r]);       // inclusive n-prefix within chunk, per t
#pragma unroll
    for (int r = 0; r < 4; ++r)
      lp[r] = (prior2 - run[r]) + (q[r] - inc[r]);   // exclusive prefix
#pragma unroll
    for (int r = 0; r < 4; ++r)
      run[r] += bcast15(inc[r]);   // carry chunk total forward

    // per-lhi-group partial over 4 t's only; cross-lhi/-wave merged in LDS
    float m = fmaxf(fmaxf(lp[0], lp[1]), fmaxf(lp[2], lp[3]));
    float s1 = 0.f, s2 = 0.f;
#pragma unroll
    for (int r = 0; r < 4; ++r) {
      float e = fexp2(lp[r] - m);
      s1 += e;
      s2 = fmaf(e, acc[r], s2);
    }
    sm[w][ch & 3][lhi][l15][0] = m;
    sm[w][ch & 3][lhi][l15][1] = s1;
    sm[w][ch & 3][lhi][l15][2] = s2;

    // stage next chunk's slice (loaded a full chunk ago), prefetch chunk+2
    *(half8*)&Abuf[cur ^ 1][wslot] = stg;
    int pf = (ch + 2 < NCHUNKS) ? ch + 2 : NCHUNKS - 1;
    stg = *(const half8*)(abase + (size_t)pf * 4096 + wslot);

    if ((ch & 3) == 3) {           // merge 32 partials (8 waves x 4 lhi) per n
      __syncthreads();
      if (tid < 64) {
        int c4 = tid >> 4, row = tid & 15;
        float M = -3.4e38f;
#pragma unroll
        for (int wv = 0; wv < 8; ++wv)
#pragma unroll
          for (int g = 0; g < 4; ++g)
            M = fmaxf(M, sm[wv][c4][g][row][0]);
        float S1 = 0.f, S2 = 0.f;
#pragma unroll
        for (int wv = 0; wv < 8; ++wv)
#pragma unroll
          for (int g = 0; g < 4; ++g) {
            float e = fexp2(sm[wv][c4][g][row][0] - M);
            S1 = fmaf(sm[wv][c4][g][row][1], e, S1);
            S2 = fmaf(sm[wv][c4][g][row][2], e, S2);
          }
        floatx4 v;
        v[0] = M; v[1] = S1; v[2] = S2; v[3] = 0.f;
        part[pbase + (size_t)((ch - 3 + c4) * 16 + row) * 8] = v;
      }
    }
    __syncthreads();               // write visible; all reads of buf[cur] done
    tgp += NC;
  }
}

// ---- combine 8 tq-partials per (b,n) -----------------------------------------
__global__ void k_combine(const floatx4* __restrict__ part, float* __restrict__ out) {
  int idx = blockIdx.x * 256 + threadIdx.x;   // 131072 = NB*NN
  const floatx4* p = part + (size_t)idx * 8;
  floatx4 v[8];
  float M = -3.4e38f;
#pragma unroll
  for (int j = 0; j < 8; ++j) { v[j] = p[j]; M = fmaxf(M, v[j][0]); }
  float s1 = 0.f, s2 = 0.f;
#pragma unroll
  for (int j = 0; j < 8; ++j) {
    float e = fexp2(v[j][0] - M);
    s1 += v[j][1] * e;
    s2 += v[j][2] * e;
  }
  out[idx] = s2 / s1 * INV_ALPHA;   // undo alpha scale on XW values
}

extern "C" void kernel_launch(void* const* d_in, const int* in_sizes, int n_in,
                              void* d_out, int out_size, void* d_ws, size_t ws_size,
                              hipStream_t stream) {
  const float* data    = (const float*)d_in[0];
  const float* targets = (const float*)d_in[1];
  const float* W       = (const float*)d_in[2];
  const float* Wm      = (const float*)d_in[3];
  float* out = (float*)d_out;

  char* ws = (char*)d_ws;
  const size_t MB = 1u << 20;
  _Float16* Wph  = (_Float16*)ws;                          // 256 KB
  _Float16* Wpl  = (_Float16*)(ws + 256 * 1024);           // 256 KB
  _Float16* Apk  = (_Float16*)(ws + 512 * 1024);           // 64 MB packed hi/lo
  floatx4* part  = (floatx4*)(ws + 512 * 1024 + 64 * MB);  // 16 MB

  k_prep<<<512, 256, 0, stream>>>(W, Wm, Wph, Wpl);
  k_prep_data<<<8192, 256, 0, stream>>>(data, Apk);
  k_fused<<<NB * 8, 512, 0, stream>>>(Apk, targets, Wph, Wpl, part);
  k_combine<<<(NB * NN) / 256, 256, 0, stream>>>(part, out);
}

// Round 11
// 182.298 us; speedup vs baseline: 2.5327x; 1.0718x over previous
//
#include <hip/hip_runtime.h>

typedef _Float16 half8 __attribute__((ext_vector_type(8)));
typedef float floatx4 __attribute__((ext_vector_type(4)));

#define NB 64
#define NN 2048
#define ND 128
#define NT 1024
#define NC 16           // n-rows per chunk
#define NCHUNKS 128     // NN / NC (full sweep per block)
#define NIV 64          // intervals of 2 chunks

// exp2-domain constants: alpha^2 = 0.5*log2(e); scaling W,targets by alpha
// makes (alpha*d)^2 sums directly usable as log2 exponents.
#define ALPHA 0.84932184f
#define INV_ALPHA 1.17741002f
#define LP2_MAJOR (-1.7369655941662063f)   // log2(0.9/3)
#define LP2_MINOR (-12.321928094887362f)   // log2(0.1/512)

// bare v_exp_f32 (input already in log2 units, always <= 0 here)
__device__ __forceinline__ float fexp2(float x) {
  float r;
  asm("v_exp_f32 %0, %1" : "=v"(r) : "v"(x));
  return r;
}

// keep-alive pin (r4-proven form: once, immediately after the loads)
#define PIN8(x) asm volatile("" : "+v"(x))

// DPP row_shr add step for 16-lane inclusive scan (zero-fill at row edge)
template <int CTRL>
__device__ __forceinline__ float dppshr_add(float x) {
  int i = __builtin_bit_cast(int, x);
  int s = __builtin_amdgcn_update_dpp(0, i, CTRL, 0xF, 0xF, true);
  return x + __builtin_bit_cast(float, s);
}
// inclusive scan over l15 within each 16-lane row
__device__ __forceinline__ float scan16(float x) {
  x = dppshr_add<0x111>(x);   // row_shr:1
  x = dppshr_add<0x112>(x);   // row_shr:2
  x = dppshr_add<0x114>(x);   // row_shr:4
  x = dppshr_add<0x118>(x);   // row_shr:8
  return x;
}
// broadcast row-lane-15 value to all 16 lanes of the row
__device__ __forceinline__ float bcast15(float x) {
  int i = __builtin_bit_cast(int, x);
  i = __builtin_amdgcn_ds_swizzle(i, 0x1F0);
  return __builtin_bit_cast(float, i);
}

// ---- prep: W_all (f32, [D][T]) -> alpha-scaled t-major f16 hi/lo [t][d] ------
__global__ void k_prep(const float* __restrict__ W, const float* __restrict__ Wm,
                       _Float16* __restrict__ Wph, _Float16* __restrict__ Wpl) {
  int idx = blockIdx.x * 256 + threadIdx.x;      // 131072 = 1024*128
  int t = idx >> 7, d = idx & 127;
  float x = (t < 512) ? W[d * 512 + t] : Wm[d * 512 + (t - 512)];
  x *= ALPHA;
  _Float16 h = (_Float16)x;
  _Float16 l = (_Float16)(x - (float)h);
  Wph[idx] = h;
  Wpl[idx] = l;
}

// ---- prep: data -> per-chunk packed [chunk: hi 2048h | lo 2048h] -------------
__global__ void k_prep_data(const float* __restrict__ data,
                            _Float16* __restrict__ Apk) {
  int idx = blockIdx.x * 256 + threadIdx.x;      // 2,097,152 threads
  int l = idx & 63, kk = (idx >> 6) & 3, ch = (idx >> 8) & 127, b = idx >> 15;
  int row = ch * 16 + (l & 15);
  int dcol = kk * 32 + (l >> 4) * 8;
  const float* src = data + ((size_t)b * NN + row) * ND + dcol;
  floatx4 a0 = *(const floatx4*)src;
  floatx4 a1 = *(const floatx4*)(src + 4);
  half8 h, lo;
#pragma unroll
  for (int j = 0; j < 4; ++j) {
    h[j] = (_Float16)a0[j];
    lo[j] = (_Float16)(a0[j] - (float)h[j]);
    h[4 + j] = (_Float16)a1[j];
    lo[4 + j] = (_Float16)(a1[j] - (float)h[4 + j]);
  }
  size_t o = ((size_t)(b * 128 + ch)) * 4096 + kk * 512 + l * 8;
  *(half8*)(Apk + o) = h;            // hi half of chunk block
  *(half8*)(Apk + o + 2048) = lo;    // lo half of chunk block
}

// ---- fused single pass: block = (b, tq); 8 waves x 16 t; streams all 2048 n --
// 2 chunks per barrier interval, LDS pair-staged double buffer.
__global__ __launch_bounds__(512, 4)
void k_fused(const _Float16* __restrict__ Apk, const float* __restrict__ targets,
             const _Float16* __restrict__ Wph, const _Float16* __restrict__ Wpl,
             floatx4* __restrict__ part) {
  int bid = blockIdx.x;
  // XCD-affinity: all 8 tq-partners of one b share bid%8 -> same XCD L2
  int xcd = bid & 7, rest = bid >> 3;
  int tq = rest & 7, b = (rest >> 3) * 8 + xcd;
  int tid = threadIdx.x;
  int w = tid >> 6, l = tid & 63;
  int l15 = l & 15, lhi = l >> 4;
  int wavebase = tq * 128 + w * 16;

  // W fragments for this wave's 16 t (A-operand role): 32 VGPRs
  half8 wh[4], wl[4];
#pragma unroll
  for (int kk = 0; kk < 4; ++kk) {
    int off = (wavebase + l15) * 128 + kk * 32 + lhi * 8;
    wh[kk] = *(const half8*)(Wph + off);
    wl[kk] = *(const half8*)(Wpl + off);
  }
#pragma unroll
  for (int kk = 0; kk < 4; ++kk) { PIN8(wh[kk]); PIN8(wl[kk]); }

  float prior2 = (tq < 4) ? LP2_MAJOR : LP2_MINOR;   // t<512 <=> tq<4
  float run[4] = {0.f, 0.f, 0.f, 0.f};               // n-prefix per t (in regs)

  const _Float16* abase = Apk + (size_t)b * 128 * 4096;
  const float* tgp = targets + (size_t)b * NN + l15;
  size_t pbase = (size_t)b * NN * 8 + tq;

  __shared__ _Float16 Abuf[2][2][4096];     // [buf][chunk-of-pair] 32 KB
  __shared__ float sm[8][4][65][3];         // lane-indexed, conflict-free ~24.4 KB

  int wslot = w * 512 + l * 8;              // this thread's 16B slice (halfs)

#define EPI(ACC, SLOT, TGOFF)                                         \
  do {                                                                \
    float tgs = tgp[TGOFF] * ALPHA;                                   \
    float q[4], inc[4], lp[4];                                        \
    _Pragma("unroll")                                                 \
    for (int r = 0; r < 4; ++r) {                                     \
      float d = tgs - ACC[r];                                         \
      q[r] = d * d;                                                   \
    }                                                                 \
    _Pragma("unroll")                                                 \
    for (int r = 0; r < 4; ++r) inc[r] = scan16(q[r]);                \
    _Pragma("unroll")                                                 \
    for (int r = 0; r < 4; ++r)                                       \
      lp[r] = (prior2 - run[r]) + (q[r] - inc[r]);                    \
    _Pragma("unroll")                                                 \
    for (int r = 0; r < 4; ++r) run[r] += bcast15(inc[r]);            \
    float m = fmaxf(fmaxf(lp[0], lp[1]), fmaxf(lp[2], lp[3]));        \
    float s1 = 0.f, s2 = 0.f;                                         \
    _Pragma("unroll")                                                 \
    for (int r = 0; r < 4; ++r) {                                     \
      float e = fexp2(lp[r] - m);                                     \
      s1 += e;                                                        \
      s2 = fmaf(e, ACC[r], s2);                                       \
    }                                                                 \
    sm[w][SLOT][l][0] = m;                                            \
    sm[w][SLOT][l][1] = s1;                                           \
    sm[w][SLOT][l][2] = s2;                                           \
  } while (0)

#define GEMM3(ACC, AH, AL)                                                        \
  do {                                                                            \
    floatx4 hh = {0.f, 0.f, 0.f, 0.f};                                            \
    floatx4 hl = {0.f, 0.f, 0.f, 0.f};                                            \
    floatx4 lh = {0.f, 0.f, 0.f, 0.f};                                            \
    _Pragma("unroll")                                                             \
    for (int kk = 0; kk < 4; ++kk) {                                              \
      hh = __builtin_amdgcn_mfma_f32_16x16x32_f16(wh[kk], AH[kk], hh, 0, 0, 0);   \
      hl = __builtin_amdgcn_mfma_f32_16x16x32_f16(wh[kk], AL[kk], hl, 0, 0, 0);   \
      lh = __builtin_amdgcn_mfma_f32_16x16x32_f16(wl[kk], AH[kk], lh, 0, 0, 0);   \
    }                                                                             \
    ACC = (hh + hl) + lh;                                                         \
  } while (0)

  // prologue: stage chunks 0,1 into buf 0; prefetch chunks 2,3 into regs
  half8 s0 = *(const half8*)(abase + wslot);
  half8 s1 = *(const half8*)(abase + 4096 + wslot);
  *(half8*)&Abuf[0][0][wslot] = s0;
  *(half8*)&Abuf[0][1][wslot] = s1;
  s0 = *(const half8*)(abase + 2 * 4096 + wslot);
  s1 = *(const half8*)(abase + 3 * 4096 + wslot);
  __syncthreads();

  for (int iv = 0; iv < NIV; ++iv) {
    int cur = iv & 1;
    // chunk A = 2*iv
    half8 ahA[4], alA[4];
#pragma unroll
    for (int kk = 0; kk < 4; ++kk) {
      ahA[kk] = *(const half8*)&Abuf[cur][0][kk * 512 + l * 8];
      alA[kk] = *(const half8*)&Abuf[cur][0][2048 + kk * 512 + l * 8];
    }
    floatx4 accA;
    GEMM3(accA, ahA, alA);
    // chunk B = 2*iv+1
    half8 ahB[4], alB[4];
#pragma unroll
    for (int kk = 0; kk < 4; ++kk) {
      ahB[kk] = *(const half8*)&Abuf[cur][1][kk * 512 + l * 8];
      alB[kk] = *(const half8*)&Abuf[cur][1][2048 + kk * 512 + l * 8];
    }
    floatx4 accB;
    GEMM3(accB, ahB, alB);

    // stage next interval's pair (loaded an interval ago); prefetch iv+2
    *(half8*)&Abuf[cur ^ 1][0][wslot] = s0;
    *(half8*)&Abuf[cur ^ 1][1][wslot] = s1;
    int pfA = 2 * iv + 4, pfB = 2 * iv + 5;
    pfA = pfA > 127 ? 127 : pfA;
    pfB = pfB > 127 ? 127 : pfB;
    s0 = *(const half8*)(abase + (size_t)pfA * 4096 + wslot);
    s1 = *(const half8*)(abase + (size_t)pfB * 4096 + wslot);

    EPI(accA, ((2 * iv) & 3), 0);
    EPI(accB, ((2 * iv + 1) & 3), 16);

    if (iv & 1) {                    // 4 chunks complete -> merge + emit
      __syncthreads();
      if (tid < 64) {
        int c4 = tid >> 4, row = tid & 15;
        float M = -3.4e38f;
#pragma unroll
        for (int wv = 0; wv < 8; ++wv)
#pragma unroll
          for (int g = 0; g < 4; ++g)
            M = fmaxf(M, sm[wv][c4][g * 16 + row][0]);
        float S1 = 0.f, S2 = 0.f;
#pragma unroll
        for (int wv = 0; wv < 8; ++wv)
#pragma unroll
          for (int g = 0; g < 4; ++g) {
            float e = fexp2(sm[wv][c4][g * 16 + row][0] - M);
            S1 = fmaf(sm[wv][c4][g * 16 + row][1], e, S1);
            S2 = fmaf(sm[wv][c4][g * 16 + row][2], e, S2);
          }
        floatx4 v;
        v[0] = M; v[1] = S1; v[2] = S2; v[3] = 0.f;
        part[pbase + (size_t)((2 * iv - 2 + c4) * 16 + row) * 8] = v;
      }
    }
    __syncthreads();
    tgp += 32;
  }
#undef EPI
#undef GEMM3
}

// ---- combine 8 tq-partials per (b,n) -----------------------------------------
__global__ void k_combine(const floatx4* __restrict__ part, float* __restrict__ out) {
  int idx = blockIdx.x * 256 + threadIdx.x;   // 131072 = NB*NN
  const floatx4* p = part + (size_t)idx * 8;
  floatx4 v[8];
  float M = -3.4e38f;
#pragma unroll
  for (int j = 0; j < 8; ++j) { v[j] = p[j]; M = fmaxf(M, v[j][0]); }
  float s1 = 0.f, s2 = 0.f;
#pragma unroll
  for (int j = 0; j < 8; ++j) {
    float e = fexp2(v[j][0] - M);
    s1 += v[j][1] * e;
    s2 += v[j][2] * e;
  }
  out[idx] = s2 / s1 * INV_ALPHA;   // undo alpha scale on XW values
}

extern "C" void kernel_launch(void* const* d_in, const int* in_sizes, int n_in,
                              void* d_out, int out_size, void* d_ws, size_t ws_size,
                              hipStream_t stream) {
  const float* data    = (const float*)d_in[0];
  const float* targets = (const float*)d_in[1];
  const float* W       = (const float*)d_in[2];
  const float* Wm      = (const float*)d_in[3];
  float* out = (float*)d_out;

  char* ws = (char*)d_ws;
  const size_t MB = 1u << 20;
  _Float16* Wph  = (_Float16*)ws;                          // 256 KB
  _Float16* Wpl  = (_Float16*)(ws + 256 * 1024);           // 256 KB
  _Float16* Apk  = (_Float16*)(ws + 512 * 1024);           // 64 MB packed hi/lo
  floatx4* part  = (floatx4*)(ws + 512 * 1024 + 64 * MB);  // 16 MB

  k_prep<<<512, 256, 0, stream>>>(W, Wm, Wph, Wpl);
  k_prep_data<<<8192, 256, 0, stream>>>(data, Apk);
  k_fused<<<NB * 8, 512, 0, stream>>>(Apk, targets, Wph, Wpl, part);
  k_combine<<<(NB * NN) / 256, 256, 0, stream>>>(part, out);
}

// Round 13
// 176.810 us; speedup vs baseline: 2.6113x; 1.0310x over previous
//
#include <hip/hip_runtime.h>

typedef _Float16 half8 __attribute__((ext_vector_type(8)));
typedef float floatx4 __attribute__((ext_vector_type(4)));

#define NB 64
#define NN 2048
#define ND 128
#define NT 1024
#define NC 16           // n-rows per chunk
#define NCHUNKS 128     // NN / NC (full sweep per block)
#define NIV 64          // intervals of 2 chunks

// exp2-domain constants: alpha^2 = 0.5*log2(e); scaling W,targets by alpha
// makes (alpha*d)^2 sums directly usable as log2 exponents.
#define ALPHA 0.84932184f
#define INV_ALPHA 1.17741002f
#define LP2_MAJOR (-1.7369655941662063f)   // log2(0.9/3)
#define LP2_MINOR (-12.321928094887362f)   // log2(0.1/512)

// bare v_exp_f32 (input already in log2 units, always <= 0 here)
__device__ __forceinline__ float fexp2(float x) {
  float r;
  asm("v_exp_f32 %0, %1" : "=v"(r) : "v"(x));
  return r;
}

// keep-alive pin (r4-proven form: once, immediately after the loads)
#define PIN8(x) asm volatile("" : "+v"(x))

// DPP row_shr add step for 16-lane inclusive scan (zero-fill at row edge)
template <int CTRL>
__device__ __forceinline__ float dppshr_add(float x) {
  int i = __builtin_bit_cast(int, x);
  int s = __builtin_amdgcn_update_dpp(0, i, CTRL, 0xF, 0xF, true);
  return x + __builtin_bit_cast(float, s);
}
// inclusive scan over l15 within each 16-lane row
__device__ __forceinline__ float scan16(float x) {
  x = dppshr_add<0x111>(x);   // row_shr:1
  x = dppshr_add<0x112>(x);   // row_shr:2
  x = dppshr_add<0x114>(x);   // row_shr:4
  x = dppshr_add<0x118>(x);   // row_shr:8
  return x;
}
// broadcast row-lane-15 value to all 16 lanes of the row
__device__ __forceinline__ float bcast15(float x) {
  int i = __builtin_bit_cast(int, x);
  i = __builtin_amdgcn_ds_swizzle(i, 0x1F0);
  return __builtin_bit_cast(float, i);
}

// ---- prep: W_all (f32, [D][T]) -> alpha-scaled t-major f16 hi/lo [t][d] ------
__global__ void k_prep(const float* __restrict__ W, const float* __restrict__ Wm,
                       _Float16* __restrict__ Wph, _Float16* __restrict__ Wpl) {
  int idx = blockIdx.x * 256 + threadIdx.x;      // 131072 = 1024*128
  int t = idx >> 7, d = idx & 127;
  float x = (t < 512) ? W[d * 512 + t] : Wm[d * 512 + (t - 512)];
  x *= ALPHA;
  _Float16 h = (_Float16)x;
  _Float16 l = (_Float16)(x - (float)h);
  Wph[idx] = h;
  Wpl[idx] = l;
}

// ---- prep: data -> per-chunk packed [chunk: hi 2048h | lo 2048h] -------------
__global__ void k_prep_data(const float* __restrict__ data,
                            _Float16* __restrict__ Apk) {
  int idx = blockIdx.x * 256 + threadIdx.x;      // 2,097,152 threads
  int l = idx & 63, kk = (idx >> 6) & 3, ch = (idx >> 8) & 127, b = idx >> 15;
  int row = ch * 16 + (l & 15);
  int dcol = kk * 32 + (l >> 4) * 8;
  const float* src = data + ((size_t)b * NN + row) * ND + dcol;
  floatx4 a0 = *(const floatx4*)src;
  floatx4 a1 = *(const floatx4*)(src + 4);
  half8 h, lo;
#pragma unroll
  for (int j = 0; j < 4; ++j) {
    h[j] = (_Float16)a0[j];
    lo[j] = (_Float16)(a0[j] - (float)h[j]);
    h[4 + j] = (_Float16)a1[j];
    lo[4 + j] = (_Float16)(a1[j] - (float)h[4 + j]);
  }
  size_t o = ((size_t)(b * 128 + ch)) * 4096 + kk * 512 + l * 8;
  *(half8*)(Apk + o) = h;            // hi half of chunk block
  *(half8*)(Apk + o + 2048) = lo;    // lo half of chunk block
}

// ---- fused single pass: block = (b, tq); 4 waves x 32 t; streams all 2048 n --
// Each A-fragment read from LDS feeds TWO t-tiles (halves LDS read traffic).
__global__ __launch_bounds__(256, 2)
void k_fused(const _Float16* __restrict__ Apk, const float* __restrict__ targets,
             const _Float16* __restrict__ Wph, const _Float16* __restrict__ Wpl,
             floatx4* __restrict__ part) {
  int bid = blockIdx.x;
  // XCD-affinity: all 8 tq-partners of one b share bid%8 -> same XCD L2
  int xcd = bid & 7, rest = bid >> 3;
  int tq = rest & 7, b = (rest >> 3) * 8 + xcd;
  int tid = threadIdx.x;
  int w = tid >> 6, l = tid & 63;
  int l15 = l & 15, lhi = l >> 4;
  int wavebase = tq * 128 + w * 32;

  // W fragments for this wave's 32 t (2 tiles): 64 VGPRs
  half8 wh[2][4], wl[2][4];
#pragma unroll
  for (int tt = 0; tt < 2; ++tt)
#pragma unroll
    for (int kk = 0; kk < 4; ++kk) {
      int off = (wavebase + tt * 16 + l15) * 128 + kk * 32 + lhi * 8;
      wh[tt][kk] = *(const half8*)(Wph + off);
      wl[tt][kk] = *(const half8*)(Wpl + off);
    }
#pragma unroll
  for (int tt = 0; tt < 2; ++tt)
#pragma unroll
    for (int kk = 0; kk < 4; ++kk) { PIN8(wh[tt][kk]); PIN8(wl[tt][kk]); }

  float prior2 = (tq < 4) ? LP2_MAJOR : LP2_MINOR;   // t<512 <=> tq<4
  float run[2][4] = {{0.f, 0.f, 0.f, 0.f}, {0.f, 0.f, 0.f, 0.f}};

  const _Float16* abase = Apk + (size_t)b * 128 * 4096;
  const float* tgp = targets + (size_t)b * NN + l15;
  size_t pbase = (size_t)b * NN * 8 + tq;

  __shared__ _Float16 Abuf[2][8192];        // [buf][2-chunk pair] 32 KB
  __shared__ float sm[4][4][65][3];         // lane-indexed, conflict-free 12.5 KB

  int t8 = tid * 8;                         // staging slice base (halfs)

#define GEMM3(ACC, TT, AH, AL)                                                      \
  do {                                                                              \
    floatx4 hh = {0.f, 0.f, 0.f, 0.f};                                              \
    floatx4 hl = {0.f, 0.f, 0.f, 0.f};                                              \
    floatx4 lh = {0.f, 0.f, 0.f, 0.f};                                              \
    _Pragma("unroll")                                                               \
    for (int kk = 0; kk < 4; ++kk) {                                                \
      hh = __builtin_amdgcn_mfma_f32_16x16x32_f16(wh[TT][kk], AH[kk], hh, 0, 0, 0); \
      hl = __builtin_amdgcn_mfma_f32_16x16x32_f16(wh[TT][kk], AL[kk], hl, 0, 0, 0); \
      lh = __builtin_amdgcn_mfma_f32_16x16x32_f16(wl[TT][kk], AH[kk], lh, 0, 0, 0); \
    }                                                                               \
    ACC = (hh + hl) + lh;                                                           \
  } while (0)

  // EPI over both t-tiles of one chunk; per-LANE partial (8 t's) into sm[w][slot][l]
#define EPI(ACC0, ACC1, SLOT, TGOFF)                                  \
  do {                                                                \
    float tgs = tgp[TGOFF] * ALPHA;                                   \
    float q[2][4], inc[2][4], lp[2][4];                               \
    _Pragma("unroll")                                                 \
    for (int r = 0; r < 4; ++r) {                                     \
      float d0 = tgs - ACC0[r], d1 = tgs - ACC1[r];                   \
      q[0][r] = d0 * d0; q[1][r] = d1 * d1;                           \
    }                                                                 \
    _Pragma("unroll")                                                 \
    for (int tt = 0; tt < 2; ++tt)                                    \
      _Pragma("unroll")                                               \
      for (int r = 0; r < 4; ++r) inc[tt][r] = scan16(q[tt][r]);      \
    _Pragma("unroll")                                                 \
    for (int tt = 0; tt < 2; ++tt)                                    \
      _Pragma("unroll")                                               \
      for (int r = 0; r < 4; ++r) {                                   \
        lp[tt][r] = (prior2 - run[tt][r]) + (q[tt][r] - inc[tt][r]);  \
        run[tt][r] += bcast15(inc[tt][r]);                            \
      }                                                               \
    float m = fmaxf(fmaxf(fmaxf(lp[0][0], lp[0][1]),                  \
                          fmaxf(lp[0][2], lp[0][3])),                 \
                    fmaxf(fmaxf(lp[1][0], lp[1][1]),                  \
                          fmaxf(lp[1][2], lp[1][3])));                \
    float s1 = 0.f, s2 = 0.f;                                         \
    _Pragma("unroll")                                                 \
    for (int r = 0; r < 4; ++r) {                                     \
      float e0 = fexp2(lp[0][r] - m), e1 = fexp2(lp[1][r] - m);       \
      s1 += e0 + e1;                                                  \
      s2 = fmaf(e0, ACC0[r], s2);                                     \
      s2 = fmaf(e1, ACC1[r], s2);                                     \
    }                                                                 \
    sm[w][SLOT][l][0] = m;                                            \
    sm[w][SLOT][l][1] = s1;                                           \
    sm[w][SLOT][l][2] = s2;                                           \
  } while (0)

  // prologue: stage interval 0 (chunks 0,1); prefetch interval 1 into regs
  half8 s0 = *(const half8*)(abase + t8);
  half8 s1_ = *(const half8*)(abase + 2048 + t8);
  half8 s2_ = *(const half8*)(abase + 4096 + t8);
  half8 s3 = *(const half8*)(abase + 6144 + t8);
  *(half8*)&Abuf[0][t8] = s0;
  *(half8*)&Abuf[0][2048 + t8] = s1_;
  *(half8*)&Abuf[0][4096 + t8] = s2_;
  *(half8*)&Abuf[0][6144 + t8] = s3;
  s0 = *(const half8*)(abase + 8192 + t8);
  s1_ = *(const half8*)(abase + 8192 + 2048 + t8);
  s2_ = *(const half8*)(abase + 8192 + 4096 + t8);
  s3 = *(const half8*)(abase + 8192 + 6144 + t8);
  __syncthreads();

  for (int iv = 0; iv < NIV; ++iv) {
    int cur = iv & 1;
    // chunk A = 2*iv
    half8 ah[4], al[4];
#pragma unroll
    for (int kk = 0; kk < 4; ++kk) {
      ah[kk] = *(const half8*)&Abuf[cur][kk * 512 + l * 8];
      al[kk] = *(const half8*)&Abuf[cur][2048 + kk * 512 + l * 8];
    }
    floatx4 accA0, accA1;
    GEMM3(accA0, 0, ah, al);
    GEMM3(accA1, 1, ah, al);
    // chunk B = 2*iv+1
#pragma unroll
    for (int kk = 0; kk < 4; ++kk) {
      ah[kk] = *(const half8*)&Abuf[cur][4096 + kk * 512 + l * 8];
      al[kk] = *(const half8*)&Abuf[cur][6144 + kk * 512 + l * 8];
    }
    floatx4 accB0, accB1;
    GEMM3(accB0, 0, ah, al);
    GEMM3(accB1, 1, ah, al);

    // stage next interval (loaded an interval ago); prefetch iv+2
    *(half8*)&Abuf[cur ^ 1][t8] = s0;
    *(half8*)&Abuf[cur ^ 1][2048 + t8] = s1_;
    *(half8*)&Abuf[cur ^ 1][4096 + t8] = s2_;
    *(half8*)&Abuf[cur ^ 1][6144 + t8] = s3;
    {
      int pf = iv + 2 > 63 ? 63 : iv + 2;
      const _Float16* pp = abase + (size_t)pf * 8192 + t8;
      s0 = *(const half8*)pp;
      s1_ = *(const half8*)(pp + 2048);
      s2_ = *(const half8*)(pp + 4096);
      s3 = *(const half8*)(pp + 6144);
    }

    EPI(accA0, accA1, ((2 * iv) & 3), 0);
    EPI(accB0, accB1, ((2 * iv + 1) & 3), 16);

    if (iv & 1) {                    // 4 chunks complete -> merge + emit
      __syncthreads();
      if (tid < 64) {
        int c4 = tid >> 4, row = tid & 15;
        // fold 16 per-lane partials: 4 waves x 4 lhi-groups (l = g*16 + row)
        float M = -3.4e38f;
#pragma unroll
        for (int wv = 0; wv < 4; ++wv)
#pragma unroll
          for (int g = 0; g < 4; ++g)
            M = fmaxf(M, sm[wv][c4][g * 16 + row][0]);
        float S1 = 0.f, S2 = 0.f;
#pragma unroll
        for (int wv = 0; wv < 4; ++wv)
#pragma unroll
          for (int g = 0; g < 4; ++g) {
            float e = fexp2(sm[wv][c4][g * 16 + row][0] - M);
            S1 = fmaf(sm[wv][c4][g * 16 + row][1], e, S1);
            S2 = fmaf(sm[wv][c4][g * 16 + row][2], e, S2);
          }
        floatx4 v;
        v[0] = M; v[1] = S1; v[2] = S2; v[3] = 0.f;
        part[pbase + (size_t)((2 * iv - 2 + c4) * 16 + row) * 8] = v;
      }
    }
    __syncthreads();
    tgp += 32;
  }
#undef EPI
#undef GEMM3
}

// ---- combine 8 tq-partials per (b,n) -----------------------------------------
__global__ void k_combine(const floatx4* __restrict__ part, float* __restrict__ out) {
  int idx = blockIdx.x * 256 + threadIdx.x;   // 131072 = NB*NN
  const floatx4* p = part + (size_t)idx * 8;
  floatx4 v[8];
  float M = -3.4e38f;
#pragma unroll
  for (int j = 0; j < 8; ++j) { v[j] = p[j]; M = fmaxf(M, v[j][0]); }
  float s1 = 0.f, s2 = 0.f;
#pragma unroll
  for (int j = 0; j < 8; ++j) {
    float e = fexp2(v[j][0] - M);
    s1 += v[j][1] * e;
    s2 += v[j][2] * e;
  }
  out[idx] = s2 / s1 * INV_ALPHA;   // undo alpha scale on XW values
}

extern "C" void kernel_launch(void* const* d_in, const int* in_sizes, int n_in,
                              void* d_out, int out_size, void* d_ws, size_t ws_size,
                              hipStream_t stream) {
  const float* data    = (const float*)d_in[0];
  const float* targets = (const float*)d_in[1];
  const float* W       = (const float*)d_in[2];
  const float* Wm      = (const float*)d_in[3];
  float* out = (float*)d_out;

  char* ws = (char*)d_ws;
  const size_t MB = 1u << 20;
  _Float16* Wph  = (_Float16*)ws;                          // 256 KB
  _Float16* Wpl  = (_Float16*)(ws + 256 * 1024);           // 256 KB
  _Float16* Apk  = (_Float16*)(ws + 512 * 1024);           // 64 MB packed hi/lo
  floatx4* part  = (floatx4*)(ws + 512 * 1024 + 64 * MB);  // 16 MB

  k_prep<<<512, 256, 0, stream>>>(W, Wm, Wph, Wpl);
  k_prep_data<<<8192, 256, 0, stream>>>(data, Apk);
  k_fused<<<NB * 8, 256, 0, stream>>>(Apk, targets, Wph, Wpl, part);
  k_combine<<<(NB * NN) / 256, 256, 0, stream>>>(part, out);
}